// Round 12
// baseline (506.798 us; speedup 1.0000x reference)
//
#include <hip/hip_runtime.h>
#include <math.h>

#define CDIM  128
#define NHEAD 8
#define DHEAD 16
#define NPAT  50000
#define NICD  591
#define NNDC  2042
#define OUTN  90
#define NEDGE 250000
#define NLAYER 2
#define ALC   640    // LDS-alpha fast-path degree cap (icd max deg ~500)

// concat offsets for CSR build (relation order: pi, ip, pn, np; dst sizes)
#define OFF0  0
#define OFF1  (NICD)
#define OFF2  (NICD + NPAT)
#define OFF3  (NICD + NPAT + NNDC)
#define NTOT  (NICD + NPAT + NNDC + NPAT)
#define NB_SCAN ((NTOT + 1023) / 1024)     // 101

#define LDP 40     // GEMM LDS row stride (bf16 elems)
#define CTILE 72   // GEMM epilogue staging row stride (bf16)
#define LOG2E 1.4426950408889634f

#define NSEG  (2 * NNDC)
#define NAGG  ((NPAT + 3) / 4)

// prep_all block ranges
#define PB_W  224                          // wprep (4*4*14)
#define PB_C  (PB_W + 16)                  // wcomp
#define PB_Q  (PB_C + 3)                   // biasq
#define PB_Z  (PB_Q + NB_SCAN)             // zero deg
#define PB_G  (PB_Z + (((NICD + NNDC) * CDIM + 255) / 256))  // gather

// scat_in ranges: 512 blocks per relation (tail-parallelism for atomics)
#define SI_PER  512
#define SI_SCAT (4 * SI_PER)               // 2048
#define SI_NWG  (((NPAT + 63) / 64) * 2)   // 1564 input-proj blocks

typedef __attribute__((ext_vector_type(8))) short bf16x8;
typedef __attribute__((ext_vector_type(4))) float f32x4;

__device__ __forceinline__ float gelu_fast(float x) {
    float x3 = x * x * x;
    float y = 0.7978845608028654f * (x + 0.044715f * x3);
    float e = exp2f(y * (2.0f * LOG2E));
    float t = 1.0f - 2.0f * __builtin_amdgcn_rcpf(e + 1.0f);
    return 0.5f * x * (1.0f + t);
}
__device__ __forceinline__ float b2f(unsigned short u) {
    union { unsigned int i; float f; } v; v.i = ((unsigned int)u) << 16; return v.f;
}
__device__ __forceinline__ unsigned short f2b(float f) {
    union { float ff; unsigned int i; } v; v.ff = f;
    unsigned int i = v.i;
    return (unsigned short)((i + 0x7FFFu + ((i >> 16) & 1u)) >> 16);  // RNE
}
__device__ __forceinline__ float2 b2x2(unsigned int u) {
    union { unsigned int i; float f; } lo, hi;
    lo.i = u << 16; hi.i = u & 0xFFFF0000u;
    return make_float2(lo.f, hi.f);
}

// ---------------------------------------------------------------------------
// Shared GEMM core (a_mode=0 bf16 A, c_mode=0 bf16 C, act=0, optional skip).
// ---------------------------------------------------------------------------
__device__ __forceinline__ void gemm_core(
    const unsigned short* __restrict__ Ap,
    const unsigned short* __restrict__ Wt, const float* __restrict__ bias,
    unsigned short* __restrict__ Cp, int ldc,
    int M, int N, int ntile, int wgid,
    const unsigned short* __restrict__ xold,
    const float* __restrict__ skipv, int skipidx,
    unsigned short* Al, unsigned short* Bl, unsigned short* Cst)
{
    int bm = (wgid / ntile) * 64, bn = (wgid % ntile) * 64;
    int t = threadIdx.x;
    int lane = t & 63, w = t >> 6;
    int wr = w >> 1, wc = w & 1;
    int quad = lane >> 4, lm = lane & 15;
    f32x4 acc[2][2] = {};
    const int srow = t >> 2;
    const int skq  = (t & 3) * 8;

    for (int k0 = 0; k0 < 128; k0 += 32) {
        {
            int row = bm + srow;
            uint4 u = make_uint4(0, 0, 0, 0);
            if (row < M)
                u = *(const uint4*)(Ap + (size_t)row * 128 + k0 + skq);
            *(uint4*)&Al[srow * LDP + skq] = u;
        }
        {
            int n = bn + srow;
            uint4 u = make_uint4(0, 0, 0, 0);
            if (n < N) u = *(const uint4*)(Wt + (size_t)n * 128 + k0 + skq);
            *(uint4*)&Bl[srow * LDP + skq] = u;
        }
        __syncthreads();
        bf16x8 af[2], bfr[2];
        #pragma unroll
        for (int i = 0; i < 2; i++) {
            af[i]  = *(const bf16x8*)&Al[(wr * 32 + i * 16 + lm) * LDP + quad * 8];
            bfr[i] = *(const bf16x8*)&Bl[(wc * 32 + i * 16 + lm) * LDP + quad * 8];
        }
        acc[0][0] = __builtin_amdgcn_mfma_f32_16x16x32_bf16(af[0], bfr[0], acc[0][0], 0, 0, 0);
        acc[0][1] = __builtin_amdgcn_mfma_f32_16x16x32_bf16(af[0], bfr[1], acc[0][1], 0, 0, 0);
        acc[1][0] = __builtin_amdgcn_mfma_f32_16x16x32_bf16(af[1], bfr[0], acc[1][0], 0, 0, 0);
        acc[1][1] = __builtin_amdgcn_mfma_f32_16x16x32_bf16(af[1], bfr[1], acc[1][1], 0, 0, 0);
        __syncthreads();
    }

    float aSk = 0.f, oneM = 0.f;
    if (skipv) {
        float sv = skipv[skipidx];
        aSk = 1.0f / (1.0f + expf(-sv));
        oneM = 1.0f - aSk;
    }
    #pragma unroll
    for (int tm = 0; tm < 2; tm++)
    #pragma unroll
    for (int tn = 0; tn < 2; tn++)
    #pragma unroll
    for (int r = 0; r < 4; r++) {
        int lrow = wr * 32 + tm * 16 + quad * 4 + r;
        int lcol = wc * 32 + tn * 16 + lm;
        int row = bm + lrow, col = bn + lcol;
        float v = acc[tm][tn][r] + (bias ? bias[col] : 0.f);
        if (skipv && row < M) v = aSk * v + oneM * b2f(xold[(size_t)row * ldc + col]);
        Cst[lrow * CTILE + lcol] = f2b(v);
    }
    __syncthreads();
    int row = t >> 2, seg = (t & 3) * 16;
    if (bm + row < M) {
        unsigned short* dst = Cp + (size_t)(bm + row) * ldc + bn + seg;
        *(uint4*)dst       = *(const uint4*)&Cst[row * CTILE + seg];
        *(uint4*)(dst + 8) = *(const uint4*)&Cst[row * CTILE + seg + 8];
    }
}

// ---------------------------------------------------------------------------
// Triple-GEMM launch (desc0 XCD-swizzled).
// ---------------------------------------------------------------------------
__global__ __launch_bounds__(256) void gemm3_kernel(
    const unsigned short* __restrict__ A0, const unsigned short* __restrict__ W0,
    const float* __restrict__ b0, unsigned short* __restrict__ C0,
    int M0, int N0, int ntile0, int nwg0,
    const unsigned short* __restrict__ A1, const unsigned short* __restrict__ W1,
    const float* __restrict__ b1, unsigned short* __restrict__ C1,
    int M1, int N1, int ntile1, int nwg01,
    const unsigned short* __restrict__ A2, const unsigned short* __restrict__ W2,
    const float* __restrict__ b2, unsigned short* __restrict__ C2,
    int M2, int N2, int ntile2,
    const float* __restrict__ skipv, int si0, int si1, int si2)
{
    __shared__ unsigned short Al[64 * LDP];
    __shared__ unsigned short Bl[64 * LDP];
    __shared__ unsigned short Cst[64 * CTILE];
    int b = blockIdx.x;
    if (b < nwg0) {
        int qq = nwg0 >> 3, rr = nwg0 & 7;
        int xcd = b & 7, idx = b >> 3;
        int wgid = (xcd < rr ? xcd * (qq + 1) : rr * (qq + 1) + (xcd - rr) * qq) + idx;
        gemm_core(A0, W0, b0, C0, N0, M0, N0, ntile0, wgid,
                  C0, skipv, si0, Al, Bl, Cst);
    } else if (b < nwg01) {
        gemm_core(A1, W1, b1, C1, N1, M1, N1, ntile1, b - nwg0,
                  C1, skipv, si1, Al, Bl, Cst);
    } else {
        gemm_core(A2, W2, b2, C2, N2, M2, N2, ntile2, b - nwg01,
                  C2, skipv, si2, Al, Bl, Cst);
    }
}

// ---------------------------------------------------------------------------
// General bf16 MFMA GEMM — used only for the output head (c_mode 1 sigmoid).
// ---------------------------------------------------------------------------
__global__ __launch_bounds__(256) void gemm_xs(
    const void* __restrict__ Ap, int a_mode, int lda,
    const unsigned short* __restrict__ Wt, const float* __restrict__ bias,
    void* __restrict__ Cp, int c_mode, int ldc,
    int M, int N, int act, int ntile,
    const unsigned short* __restrict__ xold, int ldx,
    const float* __restrict__ skipv, int skipidx)
{
    __shared__ unsigned short Al[64 * LDP];
    __shared__ unsigned short Bl[64 * LDP];
    __shared__ unsigned short Cst[64 * CTILE];
    int nwg = gridDim.x;
    int orig = blockIdx.x;
    int qq = nwg >> 3, rr = nwg & 7;
    int xcd = orig & 7, idx = orig >> 3;
    int wgid = (xcd < rr ? xcd * (qq + 1) : rr * (qq + 1) + (xcd - rr) * qq) + idx;
    int bm = (wgid / ntile) * 64, bn = (wgid % ntile) * 64;

    int t = threadIdx.x;
    int lane = t & 63, w = t >> 6;
    int wr = w >> 1, wc = w & 1;
    int quad = lane >> 4, lm = lane & 15;
    f32x4 acc[2][2] = {};
    const int srow = t >> 2;
    const int skq  = (t & 3) * 8;

    for (int k0 = 0; k0 < 128; k0 += 32) {
        {
            int row = bm + srow;
            uint4 u = make_uint4(0, 0, 0, 0);
            if (a_mode == 0) {
                if (row < M)
                    u = *(const uint4*)((const unsigned short*)Ap + (size_t)row * lda + k0 + skq);
            } else {
                float f[8] = {0.f,0.f,0.f,0.f,0.f,0.f,0.f,0.f};
                if (row < M) {
                    const float4* ap = (const float4*)((const float*)Ap + (size_t)row * lda + k0 + skq);
                    float4 u0 = ap[0], u1 = ap[1];
                    f[0]=u0.x; f[1]=u0.y; f[2]=u0.z; f[3]=u0.w;
                    f[4]=u1.x; f[5]=u1.y; f[6]=u1.z; f[7]=u1.w;
                }
                unsigned short v[8];
                for (int i = 0; i < 8; i++) v[i] = f2b(f[i]);
                u = *(uint4*)v;
            }
            *(uint4*)&Al[srow * LDP + skq] = u;
        }
        {
            int n = bn + srow;
            uint4 u = make_uint4(0, 0, 0, 0);
            if (n < N) u = *(const uint4*)(Wt + (size_t)n * 128 + k0 + skq);
            *(uint4*)&Bl[srow * LDP + skq] = u;
        }
        __syncthreads();
        bf16x8 af[2], bfr[2];
        #pragma unroll
        for (int i = 0; i < 2; i++) {
            af[i]  = *(const bf16x8*)&Al[(wr * 32 + i * 16 + lm) * LDP + quad * 8];
            bfr[i] = *(const bf16x8*)&Bl[(wc * 32 + i * 16 + lm) * LDP + quad * 8];
        }
        acc[0][0] = __builtin_amdgcn_mfma_f32_16x16x32_bf16(af[0], bfr[0], acc[0][0], 0, 0, 0);
        acc[0][1] = __builtin_amdgcn_mfma_f32_16x16x32_bf16(af[0], bfr[1], acc[0][1], 0, 0, 0);
        acc[1][0] = __builtin_amdgcn_mfma_f32_16x16x32_bf16(af[1], bfr[0], acc[1][0], 0, 0, 0);
        acc[1][1] = __builtin_amdgcn_mfma_f32_16x16x32_bf16(af[1], bfr[1], acc[1][1], 0, 0, 0);
        __syncthreads();
    }

    if (c_mode == 0) {
        #pragma unroll
        for (int tm = 0; tm < 2; tm++)
        #pragma unroll
        for (int tn = 0; tn < 2; tn++)
        #pragma unroll
        for (int r = 0; r < 4; r++) {
            int lrow = wr * 32 + tm * 16 + quad * 4 + r;
            int lcol = wc * 32 + tn * 16 + lm;
            int col = bn + lcol;
            float v = acc[tm][tn][r] + (bias ? bias[col] : 0.f);
            if (act == 1) v = fmaxf(v, 0.f);
            Cst[lrow * CTILE + lcol] = f2b(v);
        }
        __syncthreads();
        int row = t >> 2, seg = (t & 3) * 16;
        if (bm + row < M) {
            unsigned short* dst = (unsigned short*)Cp + (size_t)(bm + row) * ldc + bn + seg;
            *(uint4*)dst       = *(const uint4*)&Cst[row * CTILE + seg];
            *(uint4*)(dst + 8) = *(const uint4*)&Cst[row * CTILE + seg + 8];
        }
    } else {
        #pragma unroll
        for (int tm = 0; tm < 2; tm++)
        #pragma unroll
        for (int tn = 0; tn < 2; tn++)
        #pragma unroll
        for (int r = 0; r < 4; r++) {
            int row = bm + wr * 32 + tm * 16 + quad * 4 + r;
            int col = bn + wc * 32 + tn * 16 + lm;
            if (row >= M || col >= N) continue;
            float v = acc[tm][tn][r] + (bias ? bias[col] : 0.f);
            if (act == 1) v = fmaxf(v, 0.f);
            else if (act == 2) v = 1.0f / (1.0f + expf(-v));
            ((float*)Cp)[(size_t)row * ldc + col] = v;
        }
    }
}

// ---------------------------------------------------------------------------
// MERGED prep: wprep + wcomp + biasq + deg zeroing + embedding gathers.
// ---------------------------------------------------------------------------
__global__ __launch_bounds__(256) void prep_all_kernel(
    const float* __restrict__ qw, const float* __restrict__ aw,
    const float* __restrict__ w_in, const float* __restrict__ w_out,
    unsigned short* __restrict__ Wb0, unsigned short* __restrict__ Wb1,
    unsigned short* __restrict__ Wb2, unsigned short* __restrict__ Wtaw,
    unsigned short* __restrict__ Wtin, unsigned short* __restrict__ Wtout,
    const float* __restrict__ kw, const float* __restrict__ vw,
    const float* __restrict__ a_rel, const float* __restrict__ m_rel,
    const float* __restrict__ kb, const float* __restrict__ vb,
    float* __restrict__ bb0, float* __restrict__ bb1, float* __restrict__ bb2,
    const float* __restrict__ qb,
    int* __restrict__ deg,
    const float* __restrict__ emb_icd, const int* __restrict__ x_icd,
    unsigned short* __restrict__ xb1,
    const float* __restrict__ emb_ndc, const int* __restrict__ x_ndc,
    unsigned short* __restrict__ xb2)
{
    __shared__ float tile[32][33];
    int b = blockIdx.x;
    int tid = threadIdx.x;
    if (b < PB_W) {
        int z = b >> 4, rem = b & 15;
        int by = rem >> 2, bx = rem & 3;
        const float* s; unsigned short* d; int N = 128;
        if (z < 2)       { s = qw + (size_t)z * 3 * 16384;               d = Wb0 + (size_t)z * 640 * 128; }
        else if (z < 4)  { s = qw + 16384 + (size_t)(z - 2) * 3 * 16384; d = Wb1 + (size_t)(z - 2) * 384 * 128; }
        else if (z < 6)  { s = qw + 2 * 16384 + (size_t)(z - 4) * 3 * 16384; d = Wb2 + (size_t)(z - 4) * 384 * 128; }
        else if (z < 12) { s = aw + (size_t)(z - 6) * 16384;             d = Wtaw + (size_t)(z - 6) * 16384; }
        else if (z == 12){ s = w_in;  d = Wtin; }
        else             { s = w_out; d = Wtout; N = OUTN; }
        int k0 = bx * 32, n0 = by * 32;
        int tx = tid & 31, ty = tid >> 5;
        for (int i = 0; i < 32; i += 8) {
            int k = k0 + ty + i, n = n0 + tx;
            tile[ty + i][tx] = (k < 128 && n < N) ? s[(size_t)k * N + n] : 0.f;
        }
        __syncthreads();
        for (int i = 0; i < 32; i += 8) {
            int n = n0 + ty + i, k = k0 + tx;
            if (n < N && k < 128) d[(size_t)n * 128 + k] = f2b(tile[tx][ty + i]);
        }
    } else if (b < PB_C) {
        int s = b - PB_W;
        int l = s >> 3, j = s & 7;
        int ty, isV, r, rowoff, nw;
        unsigned short* Wb; float* bb;
        switch (j) {
          case 0: ty=0; isV=0; r=0; Wb=Wb0; bb=bb0; rowoff=128; nw=640; break;
          case 1: ty=0; isV=1; r=0; Wb=Wb0; bb=bb0; rowoff=256; nw=640; break;
          case 2: ty=0; isV=0; r=2; Wb=Wb0; bb=bb0; rowoff=384; nw=640; break;
          case 3: ty=0; isV=1; r=2; Wb=Wb0; bb=bb0; rowoff=512; nw=640; break;
          case 4: ty=1; isV=0; r=1; Wb=Wb1; bb=bb1; rowoff=128; nw=384; break;
          case 5: ty=1; isV=1; r=1; Wb=Wb1; bb=bb1; rowoff=256; nw=384; break;
          case 6: ty=2; isV=0; r=3; Wb=Wb2; bb=bb2; rowoff=128; nw=384; break;
          default:ty=2; isV=1; r=3; Wb=Wb2; bb=bb2; rowoff=256; nw=384; break;
        }
        const float* W = (isV ? vw : kw) + (size_t)(l * 3 + ty) * 16384;
        const float* A = (isV ? m_rel : a_rel) + (size_t)(l * 4 + r) * 2048;
        const float* B = (isV ? vb : kb) + (size_t)(l * 3 + ty) * 128;
        unsigned short* dst = Wb + (size_t)l * nw * 128 + (size_t)rowoff * 128;
        float* bdst = bb + (size_t)l * nw + rowoff;
        int n = tid & 127;
        int kh = tid >> 7;
        int h = n >> 4, e = n & 15;
        float Ar[16];
        #pragma unroll
        for (int d = 0; d < 16; d++) Ar[d] = A[h * 256 + d * 16 + e];
        for (int k = kh * 64; k < kh * 64 + 64; k++) {
            float acc = 0.f;
            const float* wr = W + (size_t)k * 128 + h * 16;
            #pragma unroll
            for (int d = 0; d < 16; d++) acc += wr[d] * Ar[d];
            dst[(size_t)n * 128 + k] = f2b(acc);
        }
        if (kh == 0) {
            float acc = 0.f;
            const float* br = B + h * 16;
            #pragma unroll
            for (int d = 0; d < 16; d++) acc += br[d] * Ar[d];
            bdst[n] = acc;
        }
    } else if (b < PB_Q) {
        int t = (b - PB_C) * 256 + tid;
        if (t < 6 * 128) {
            int g = t >> 7, c = t & 127;
            int l = g / 3, ty = g % 3;
            float v = qb[g * 128 + c];
            if (ty == 0) bb0[l * 640 + c] = v;
            else if (ty == 1) bb1[l * 384 + c] = v;
            else bb2[l * 384 + c] = v;
        }
    } else if (b < PB_Z) {
        int base = (b - PB_Q) * 1024 + tid * 4;
        if (base + 3 < NTOT) *(int4*)(deg + base) = make_int4(0, 0, 0, 0);
        else for (int i = 0; i < 4; i++) if (base + i < NTOT) deg[base + i] = 0;
    } else {
        int t = (b - PB_Z) * 256 + tid;
        int totA = NICD * CDIM;
        if (t < totA) {
            int r = t >> 7, c = t & 127;
            xb1[t] = f2b(fmaxf(emb_icd[(size_t)x_icd[r] * CDIM + c], 0.f));
        } else if (t < totA + NNDC * CDIM) {
            int u = t - totA;
            int r = u >> 7, c = u & 127;
            xb2[u] = f2b(fmaxf(emb_ndc[(size_t)x_ndc[r] * CDIM + c], 0.f));
        }
    }
}

// ---------------------------------------------------------------------------
// Histogram: grid (256, 4) — more blocks to hide atomic latency.
// ---------------------------------------------------------------------------
__global__ __launch_bounds__(256) void hist4_kernel(
    const int* __restrict__ d0, const int* __restrict__ d1,
    const int* __restrict__ d2, const int* __restrict__ d3,
    int* __restrict__ deg)
{
    __shared__ int lh[2048];
    int rel = blockIdx.y;
    int t = threadIdx.x;
    const int* dp = (rel == 0) ? d0 : (rel == 1) ? d1 : (rel == 2) ? d2 : d3;
    int off = (rel == 0) ? OFF0 : (rel == 1) ? OFF1 : (rel == 2) ? OFF2 : OFF3;
    if (rel == 1 || rel == 3) {
        for (int e = blockIdx.x * 256 + t; e < NEDGE; e += gridDim.x * 256)
            atomicAdd(&deg[off + dp[e]], 1);
    } else {
        int nb = (rel == 0) ? NICD : NNDC;
        for (int i = t; i < nb; i += 256) lh[i] = 0;
        __syncthreads();
        for (int e = blockIdx.x * 256 + t; e < NEDGE; e += gridDim.x * 256)
            atomicAdd(&lh[dp[e]], 1);
        __syncthreads();
        for (int i = t; i < nb; i += 256) {
            int v = lh[i];
            if (v) atomicAdd(&deg[off + i], v);
        }
    }
}

__global__ __launch_bounds__(256) void scanA_kernel(
    const int* __restrict__ deg, int* __restrict__ part, int n)
{
    __shared__ int red[256];
    int b = blockIdx.x, t = threadIdx.x;
    int base = b * 1024 + t * 4;
    int s = 0;
    if (base + 3 < n) {
        int4 v = *(const int4*)(deg + base);
        s = v.x + v.y + v.z + v.w;
    } else {
        for (int i = 0; i < 4; i++) if (base + i < n) s += deg[base + i];
    }
    red[t] = s;
    __syncthreads();
    for (int o = 128; o; o >>= 1) { if (t < o) red[t] += red[t + o]; __syncthreads(); }
    if (t == 0) part[b] = red[0];
}

// scanC2: includes inline prefix-of-part (replaces scanB dispatch)
__global__ __launch_bounds__(256) void scanC2_kernel(
    const int* __restrict__ deg, const int* __restrict__ part,
    int* __restrict__ rp0, int* __restrict__ rp1,
    int* __restrict__ rp2, int* __restrict__ rp3,
    int* __restrict__ cursor, int n)
{
    __shared__ int red[256];
    __shared__ int pre[128];
    int b = blockIdx.x, t = threadIdx.x;
    if (t < 128) pre[t] = (t < b) ? part[t] : 0;
    __syncthreads();
    for (int o = 64; o; o >>= 1) { if (t < o) pre[t] += pre[t + o]; __syncthreads(); }
    int pbase = pre[0];
    __syncthreads();

    int base = b * 1024 + t * 4;
    int v[4] = {0, 0, 0, 0};
    if (base + 3 < n) {
        int4 q = *(const int4*)(deg + base);
        v[0] = q.x; v[1] = q.y; v[2] = q.z; v[3] = q.w;
    } else {
        for (int i = 0; i < 4; i++) if (base + i < n) v[i] = deg[base + i];
    }
    red[t] = v[0] + v[1] + v[2] + v[3];
    __syncthreads();
    for (int off = 1; off < 256; off <<= 1) {
        int y = (t >= off) ? red[t - off] : 0;
        __syncthreads();
        red[t] += y;
        __syncthreads();
    }
    int run = pbase + ((t == 0) ? 0 : red[t - 1]);
    for (int i = 0; i < 4; i++) {
        int g = base + i;
        if (g < n) {
            cursor[g] = run;
            int r, loc;
            if      (g < OFF1) { r = 0; loc = g; }
            else if (g < OFF2) { r = 1; loc = g - OFF1; }
            else if (g < OFF3) { r = 2; loc = g - OFF2; }
            else               { r = 3; loc = g - OFF3; }
            int Sl = run - r * NEDGE;
            ((r == 0) ? rp0 : (r == 1) ? rp1 : (r == 2) ? rp2 : rp3)[loc] = Sl;
            run += v[i];
        }
    }
    if (b == 0 && t == 0) {
        rp0[NICD] = NEDGE; rp1[NPAT] = NEDGE; rp2[NNDC] = NEDGE; rp3[NPAT] = NEDGE;
    }
}

// ---------------------------------------------------------------------------
// MERGED scatter + input-projection GEMM.
// blocks [0, SI_SCAT): scatter, rel = b>>9, chunk = b&511 (512 blocks/rel
// for atomic-latency tail parallelism).
// blocks [SI_SCAT, SI_SCAT+SI_NWG): input proj (fp32 A, relu, bf16 C).
// ---------------------------------------------------------------------------
__global__ __launch_bounds__(256) void scat_in_kernel(
    const int* __restrict__ s0, const int* __restrict__ d0,
    const int* __restrict__ s1, const int* __restrict__ d1,
    const int* __restrict__ s2, const int* __restrict__ d2,
    const int* __restrict__ s3, const int* __restrict__ d3,
    int* __restrict__ cursor, unsigned int* __restrict__ es,
    const float* __restrict__ Axp, const unsigned short* __restrict__ Wtin,
    const float* __restrict__ b_in, unsigned short* __restrict__ xb0)
{
    __shared__ __align__(16) char smem[19456];
    int b = blockIdx.x;
    int t = threadIdx.x;
    if (b < SI_SCAT) {
        int* lcnt = (int*)smem;
        int* lbase = lcnt + 2048;
        int rel = b >> 9;
        int bx = b & (SI_PER - 1);
        const int* sp = (rel == 0) ? s0 : (rel == 1) ? s1 : (rel == 2) ? s2 : s3;
        const int* dp = (rel == 0) ? d0 : (rel == 1) ? d1 : (rel == 2) ? d2 : d3;
        int off = (rel == 0) ? OFF0 : (rel == 1) ? OFF1 : (rel == 2) ? OFF2 : OFF3;
        if (rel == 1 || rel == 3) {
            for (int e = bx * 256 + t; e < NEDGE; e += SI_PER * 256) {
                int d = dp[e];
                int p = atomicAdd(&cursor[off + d], 1);
                es[p] = ((unsigned int)sp[e] << 16) | (unsigned int)d;
            }
        } else {
            int nb = (rel == 0) ? NICD : NNDC;
            int per = (NEDGE + SI_PER - 1) / SI_PER;
            int e0 = bx * per, e1 = min(e0 + per, NEDGE);
            for (int i = t; i < nb; i += 256) lcnt[i] = 0;
            __syncthreads();
            for (int e = e0 + t; e < e1; e += 256) atomicAdd(&lcnt[dp[e]], 1);
            __syncthreads();
            for (int i = t; i < nb; i += 256) {
                int c = lcnt[i];
                lbase[i] = c ? atomicAdd(&cursor[off + i], c) : 0;
                lcnt[i] = 0;
            }
            __syncthreads();
            for (int e = e0 + t; e < e1; e += 256) {
                int d = dp[e];
                int p = lbase[d] + atomicAdd(&lcnt[d], 1);
                es[p] = ((unsigned int)sp[e] << 16) | (unsigned int)d;
            }
        }
    } else {
        // input-projection GEMM: M=NPAT, N=128, ntile=2, A fp32, relu, bf16 C
        unsigned short* Al = (unsigned short*)smem;
        unsigned short* Bl = Al + 64 * LDP;
        unsigned short* Cst = Bl + 64 * LDP;
        int u = b - SI_SCAT;
        int nwg = SI_NWG;
        int qq = nwg >> 3, rr = nwg & 7;
        int xcd = u & 7, idx = u >> 3;
        int wgid = (xcd < rr ? xcd * (qq + 1) : rr * (qq + 1) + (xcd - rr) * qq) + idx;
        int bm = (wgid >> 1) * 64, bn = (wgid & 1) * 64;

        int lane = t & 63, w = t >> 6;
        int wr = w >> 1, wc = w & 1;
        int quad = lane >> 4, lm = lane & 15;
        f32x4 acc[2][2] = {};
        const int srow = t >> 2;
        const int skq  = (t & 3) * 8;

        for (int k0 = 0; k0 < 128; k0 += 32) {
            {
                int row = bm + srow;
                float f[8] = {0.f,0.f,0.f,0.f,0.f,0.f,0.f,0.f};
                if (row < NPAT) {
                    const float4* ap = (const float4*)(Axp + (size_t)row * 128 + k0 + skq);
                    float4 u0 = ap[0], u1 = ap[1];
                    f[0]=u0.x; f[1]=u0.y; f[2]=u0.z; f[3]=u0.w;
                    f[4]=u1.x; f[5]=u1.y; f[6]=u1.z; f[7]=u1.w;
                }
                unsigned short v[8];
                for (int i = 0; i < 8; i++) v[i] = f2b(f[i]);
                *(uint4*)&Al[srow * LDP + skq] = *(uint4*)v;
            }
            {
                int n = bn + srow;
                *(uint4*)&Bl[srow * LDP + skq] = *(const uint4*)(Wtin + (size_t)n * 128 + k0 + skq);
            }
            __syncthreads();
            bf16x8 af[2], bfr[2];
            #pragma unroll
            for (int i = 0; i < 2; i++) {
                af[i]  = *(const bf16x8*)&Al[(wr * 32 + i * 16 + lm) * LDP + quad * 8];
                bfr[i] = *(const bf16x8*)&Bl[(wc * 32 + i * 16 + lm) * LDP + quad * 8];
            }
            acc[0][0] = __builtin_amdgcn_mfma_f32_16x16x32_bf16(af[0], bfr[0], acc[0][0], 0, 0, 0);
            acc[0][1] = __builtin_amdgcn_mfma_f32_16x16x32_bf16(af[0], bfr[1], acc[0][1], 0, 0, 0);
            acc[1][0] = __builtin_amdgcn_mfma_f32_16x16x32_bf16(af[1], bfr[0], acc[1][0], 0, 0, 0);
            acc[1][1] = __builtin_amdgcn_mfma_f32_16x16x32_bf16(af[1], bfr[1], acc[1][1], 0, 0, 0);
            __syncthreads();
        }
        #pragma unroll
        for (int tm = 0; tm < 2; tm++)
        #pragma unroll
        for (int tn = 0; tn < 2; tn++)
        #pragma unroll
        for (int r = 0; r < 4; r++) {
            int lrow = wr * 32 + tm * 16 + quad * 4 + r;
            int lcol = wc * 32 + tn * 16 + lm;
            float v = acc[tm][tn][r] + b_in[bn + lcol];
            v = fmaxf(v, 0.f);
            Cst[lrow * CTILE + lcol] = f2b(v);
        }
        __syncthreads();
        int row = t >> 2, seg = (t & 3) * 16;
        if (bm + row < NPAT) {
            unsigned short* dst = xb0 + (size_t)(bm + row) * 128 + bn + seg;
            *(uint4*)dst       = *(const uint4*)&Cst[row * CTILE + seg];
            *(uint4*)(dst + 8) = *(const uint4*)&Cst[row * CTILE + seg + 8];
        }
    }
}

__device__ __forceinline__ float dot16_bf(const unsigned short* a,
                                          const unsigned short* b) {
    const uint4* ap = (const uint4*)a;
    const uint4* bp = (const uint4*)b;
    uint4 a0 = ap[0], a1 = ap[1], b0 = bp[0], b1 = bp[1];
    unsigned int au[8] = {a0.x, a0.y, a0.z, a0.w, a1.x, a1.y, a1.z, a1.w};
    unsigned int bu[8] = {b0.x, b0.y, b0.z, b0.w, b1.x, b1.y, b1.z, b1.w};
    float acc = 0.f;
    #pragma unroll
    for (int j = 0; j < 8; j++) {
        float2 x = b2x2(au[j]), y = b2x2(bu[j]);
        acc += x.x * y.x + x.y * y.y;
    }
    return acc;
}

__device__ __forceinline__ float dot16_q(uint4 a0, uint4 a1,
                                         const unsigned short* b) {
    const uint4* bp = (const uint4*)b;
    uint4 b0 = bp[0], b1 = bp[1];
    unsigned int au[8] = {a0.x, a0.y, a0.z, a0.w, a1.x, a1.y, a1.z, a1.w};
    unsigned int bu[8] = {b0.x, b0.y, b0.z, b0.w, b1.x, b1.y, b1.z, b1.w};
    float acc = 0.f;
    #pragma unroll
    for (int j = 0; j < 8; j++) {
        float2 x = b2x2(au[j]), y = b2x2(bu[j]);
        acc += x.x * y.x + x.y * y.y;
    }
    return acc;
}

// ---------------------------------------------------------------------------
// seg kernel (icd/ndc-dst), one workgroup per dst node, grid.y = relation.
// ---------------------------------------------------------------------------
__global__ __launch_bounds__(256) void seg_kernel(
    const int* __restrict__ rpA, const unsigned int* __restrict__ esA,
    const unsigned short* __restrict__ qA, int ldqA,
    const unsigned short* __restrict__ krA, const unsigned short* __restrict__ vrA, int ldsA,
    const float* __restrict__ prelA, float* __restrict__ alphaA,
    unsigned short* __restrict__ aggA, int ndA,
    const int* __restrict__ rpB, const unsigned int* __restrict__ esB,
    const unsigned short* __restrict__ qB, int ldqB,
    const unsigned short* __restrict__ krB, const unsigned short* __restrict__ vrB, int ldsB,
    const float* __restrict__ prelB, float* __restrict__ alphaB,
    unsigned short* __restrict__ aggB, int ndB)
{
    __shared__ float wred[4][8];
    __shared__ float sinv[8];
    __shared__ float p3f[4][64][2];
    __shared__ float wl[ALC * NHEAD];
    __shared__ unsigned short sl[ALC];
    int rel = blockIdx.y;
    int n = blockIdx.x;
    const int* rp            = rel ? rpB : rpA;
    const unsigned int* es   = rel ? esB : esA;
    const unsigned short* q  = rel ? qB : qA;
    int ldq                  = rel ? ldqB : ldqA;
    const unsigned short* kr = rel ? krB : krA;
    const unsigned short* vr = rel ? vrB : vrA;
    int ldsrc                = rel ? ldsB : ldsA;
    const float* prel        = rel ? prelB : prelA;
    float* alpha             = rel ? alphaB : alphaA;
    unsigned short* agg      = rel ? aggB : aggA;
    int nd                   = rel ? ndB : ndA;
    if (n >= nd) return;

    int r0 = rp[n], deg = rp[n + 1] - r0;
    int t = threadIdx.x;
    int h = t & 7, j = t >> 3;
    int lane = t & 63, wv = t >> 6;
    const unsigned short* qrow = q + (size_t)n * ldq + h * DHEAD;
    uint4 qa = ((const uint4*)qrow)[0], qb = ((const uint4*)qrow)[1];
    float ph = prel[h] * 0.25f * LOG2E;

    if (deg <= ALC) {
        for (int i = t; i < deg; i += 256) sl[i] = (unsigned short)(es[r0 + i] >> 16);
        __syncthreads();

        float mx = -1e30f;
        int i = j;
        for (; i + 96 < deg; i += 128) {
            int s0 = sl[i], s1 = sl[i + 32], s2 = sl[i + 64], s3 = sl[i + 96];
            float a0 = dot16_q(qa, qb, kr + (size_t)s0 * ldsrc + h * DHEAD) * ph;
            float a1 = dot16_q(qa, qb, kr + (size_t)s1 * ldsrc + h * DHEAD) * ph;
            float a2 = dot16_q(qa, qb, kr + (size_t)s2 * ldsrc + h * DHEAD) * ph;
            float a3 = dot16_q(qa, qb, kr + (size_t)s3 * ldsrc + h * DHEAD) * ph;
            wl[(i)      * NHEAD + h] = a0;
            wl[(i + 32) * NHEAD + h] = a1;
            wl[(i + 64) * NHEAD + h] = a2;
            wl[(i + 96) * NHEAD + h] = a3;
            mx = fmaxf(mx, fmaxf(fmaxf(a0, a1), fmaxf(a2, a3)));
        }
        for (; i < deg; i += 32) {
            int s0 = sl[i];
            float a = dot16_q(qa, qb, kr + (size_t)s0 * ldsrc + h * DHEAD) * ph;
            wl[i * NHEAD + h] = a;
            mx = fmaxf(mx, a);
        }
        mx = fmaxf(mx, __shfl_xor(mx, 8));
        mx = fmaxf(mx, __shfl_xor(mx, 16));
        mx = fmaxf(mx, __shfl_xor(mx, 32));
        if (lane < 8) wred[wv][h] = mx;
        __syncthreads();
        float m = fmaxf(fmaxf(wred[0][h], wred[1][h]), fmaxf(wred[2][h], wred[3][h]));
        __syncthreads();

        float sm = 0.f;
        for (i = j; i < deg; i += 32) {
            float e = exp2f(wl[i * NHEAD + h] - m);
            wl[i * NHEAD + h] = e;
            sm += e;
        }
        sm += __shfl_xor(sm, 8);
        sm += __shfl_xor(sm, 16);
        sm += __shfl_xor(sm, 32);
        if (lane < 8) wred[wv][h] = sm;
        __syncthreads();
        if (t < 8) {
            float s = wred[0][t] + wred[1][t] + wred[2][t] + wred[3][t];
            sinv[t] = (s > 0.f) ? 1.0f / s : 0.f;
        }
        __syncthreads();

        int g = t >> 6, l = t & 63;
        int hh = l >> 3;
        float acc0 = 0.f, acc1 = 0.f;
        i = g;
        for (; i + 28 < deg; i += 32) {
            int e0 = sl[i],      e1 = sl[i + 4],  e2 = sl[i + 8],  e3 = sl[i + 12];
            int e4 = sl[i + 16], e5 = sl[i + 20], e6 = sl[i + 24], e7 = sl[i + 28];
            unsigned int u0 = *(const unsigned int*)(vr + (size_t)e0 * ldsrc + 2 * l);
            unsigned int u1 = *(const unsigned int*)(vr + (size_t)e1 * ldsrc + 2 * l);
            unsigned int u2 = *(const unsigned int*)(vr + (size_t)e2 * ldsrc + 2 * l);
            unsigned int u3 = *(const unsigned int*)(vr + (size_t)e3 * ldsrc + 2 * l);
            unsigned int u4 = *(const unsigned int*)(vr + (size_t)e4 * ldsrc + 2 * l);
            unsigned int u5 = *(const unsigned int*)(vr + (size_t)e5 * ldsrc + 2 * l);
            unsigned int u6 = *(const unsigned int*)(vr + (size_t)e6 * ldsrc + 2 * l);
            unsigned int u7 = *(const unsigned int*)(vr + (size_t)e7 * ldsrc + 2 * l);
            float w0 = wl[(i)      * NHEAD + hh], w1 = wl[(i + 4)  * NHEAD + hh];
            float w2 = wl[(i + 8)  * NHEAD + hh], w3 = wl[(i + 12) * NHEAD + hh];
            float w4 = wl[(i + 16) * NHEAD + hh], w5 = wl[(i + 20) * NHEAD + hh];
            float w6 = wl[(i + 24) * NHEAD + hh], w7 = wl[(i + 28) * NHEAD + hh];
            float2 v0 = b2x2(u0), v1 = b2x2(u1), v2 = b2x2(u2), v3 = b2x2(u3);
            float2 v4 = b2x2(u4), v5 = b2x2(u5), v6 = b2x2(u6), v7 = b2x2(u7);
            acc0 += w0 * v0.x + w1 * v1.x + w2 * v2.x + w3 * v3.x
                  + w4 * v4.x + w5 * v5.x + w6 * v6.x + w7 * v7.x;
            acc1 += w0 * v0.y + w1 * v1.y + w2 * v2.y + w3 * v3.y
                  + w4 * v4.y + w5 * v5.y + w6 * v6.y + w7 * v7.y;
        }
        for (; i < deg; i += 4) {
            int e0 = sl[i];
            unsigned int u0 = *(const unsigned int*)(vr + (size_t)e0 * ldsrc + 2 * l);
            float w0 = wl[i * NHEAD + hh];
            float2 v0 = b2x2(u0);
            acc0 += w0 * v0.x;
            acc1 += w0 * v0.y;
        }
        p3f[g][l][0] = acc0;
        p3f[g][l][1] = acc1;
        __syncthreads();
        if (t < 128) {
            int c = t;
            float v = p3f[0][c >> 1][c & 1] + p3f[1][c >> 1][c & 1]
                    + p3f[2][c >> 1][c & 1] + p3f[3][c >> 1][c & 1];
            agg[(size_t)n * CDIM + c] = f2b(gelu_fast(v * sinv[c >> 4]));
        }
    } else {
        float* p3 = (float*)p3f;
        float mx = -1e30f;
        for (int i = j; i < deg; i += 32) {
            int sn = es[r0 + i] >> 16;
            float a = dot16_q(qa, qb, kr + (size_t)sn * ldsrc + h * DHEAD) * ph;
            alpha[(size_t)(r0 + i) * NHEAD + h] = a;
            mx = fmaxf(mx, a);
        }
        mx = fmaxf(mx, __shfl_xor(mx, 8));
        mx = fmaxf(mx, __shfl_xor(mx, 16));
        mx = fmaxf(mx, __shfl_xor(mx, 32));
        if (lane < 8) wred[wv][h] = mx;
        __syncthreads();
        float m = fmaxf(fmaxf(wred[0][h], wred[1][h]), fmaxf(wred[2][h], wred[3][h]));
        __syncthreads();

        float sm = 0.f;
        for (int i = j; i < deg; i += 32) {
            size_t ai = (size_t)(r0 + i) * NHEAD + h;
            float e = exp2f(alpha[ai] - m);
            alpha[ai] = e;
            sm += e;
        }
        sm += __shfl_xor(sm, 8);
        sm += __shfl_xor(sm, 16);
        sm += __shfl_xor(sm, 32);
        if (lane < 8) wred[wv][h] = sm;
        __syncthreads();
        if (t < 8) {
            float s = wred[0][t] + wred[1][t] + wred[2][t] + wred[3][t];
            sinv[t] = (s > 0.f) ? 1.0f / s : 0.f;
        }
        __syncthreads();

        int c = t & 127, half = t >> 7;
        float hsi = sinv[c >> 4];
        float acc = 0.f;
        int i = half;
        for (; i + 6 < deg; i += 8) {
            unsigned int e0 = es[r0 + i],     e1 = es[r0 + i + 2];
            unsigned int e2 = es[r0 + i + 4], e3 = es[r0 + i + 6];
            float w0 = alpha[(size_t)(r0 + i)     * NHEAD + (c >> 4)];
            float w1 = alpha[(size_t)(r0 + i + 2) * NHEAD + (c >> 4)];
            float w2 = alpha[(size_t)(r0 + i + 4) * NHEAD + (c >> 4)];
            float w3 = alpha[(size_t)(r0 + i + 6) * NHEAD + (c >> 4)];
            float v0 = b2f(vr[(size_t)(e0 >> 16) * ldsrc + c]);
            float v1 = b2f(vr[(size_t)(e1 >> 16) * ldsrc + c]);
            float v2 = b2f(vr[(size_t)(e2 >> 16) * ldsrc + c]);
            float v3 = b2f(vr[(size_t)(e3 >> 16) * ldsrc + c]);
            acc += w0 * v0 + w1 * v1 + w2 * v2 + w3 * v3;
        }
        for (; i < deg; i += 2) {
            unsigned int e0 = es[r0 + i];
            float w0 = alpha[(size_t)(r0 + i) * NHEAD + (c >> 4)];
            acc += w0 * b2f(vr[(size_t)(e0 >> 16) * ldsrc + c]);
        }
        p3[t] = acc * hsi;
        __syncthreads();
        if (half == 0) agg[(size_t)n * CDIM + c] = f2b(gelu_fast(p3[c] + p3[128 + c]));
    }
}

// ---------------------------------------------------------------------------
// agg2 kernel (patient-dst), one wave per patient.
// ---------------------------------------------------------------------------
__global__ __launch_bounds__(256) void agg2_kernel(
    const int* __restrict__ rp1, const unsigned int* __restrict__ es1,
    const int* __restrict__ rp3, const unsigned int* __restrict__ es3,
    const unsigned short* __restrict__ q, int ldq,
    const unsigned short* __restrict__ kr1, const unsigned short* __restrict__ vr1, int ld1,
    const unsigned short* __restrict__ kr3, const unsigned short* __restrict__ vr3, int ld3,
    const float* __restrict__ prel1, const float* __restrict__ prel3,
    unsigned short* __restrict__ agg, int nd)
{
    __shared__ float wls[4][128 * NHEAD];
    __shared__ int slo[4][128];
    int wv  = threadIdx.x >> 6;
    int wid = (blockIdx.x * 256 + threadIdx.x) >> 6;
    int lane = threadIdx.x & 63;
    if (wid >= nd) return;
    float* wl = wls[wv];
    int* sl = slo[wv];
    int h = lane & 7, j = lane >> 3;
    int hc = lane >> 3;
    const unsigned short* qbase = q + (size_t)wid * ldq;

    int r0a = rp1[wid], degA = rp1[wid + 1] - r0a;
    int r0b = rp3[wid], degB = rp3[wid + 1] - r0b;

    float o0, o1;
    if (degA <= 64 && degB <= 64) {
        const unsigned short* qrow = qbase + h * DHEAD;
        uint4 qa = ((const uint4*)qrow)[0], qb = ((const uint4*)qrow)[1];
        float phA = prel1[h] * 0.25f * LOG2E;
        float phB = prel3[h] * 0.25f * LOG2E;
        int dOfs = (int)(kr3 - kr1);
        float mA = -1e30f, mB = -1e30f;
        for (int i = j; i < degA; i += 8) {
            int sn = es1[r0a + i] >> 16;
            int off = sn * ld1;
            float a = dot16_q(qa, qb, kr1 + off + h * DHEAD) * phA;
            wl[i * NHEAD + h] = a;
            if (h == 0) sl[i] = off;
            mA = fmaxf(mA, a);
        }
        for (int i = j; i < degB; i += 8) {
            int sn = es3[r0b + i] >> 16;
            int off = sn * ld3;
            float a = dot16_q(qa, qb, kr3 + off + h * DHEAD) * phB;
            wl[(degA + i) * NHEAD + h] = a;
            if (h == 0) sl[degA + i] = dOfs + off;
            mB = fmaxf(mB, a);
        }
        mA = fmaxf(mA, __shfl_xor(mA, 8));   mB = fmaxf(mB, __shfl_xor(mB, 8));
        mA = fmaxf(mA, __shfl_xor(mA, 16));  mB = fmaxf(mB, __shfl_xor(mB, 16));
        mA = fmaxf(mA, __shfl_xor(mA, 32));  mB = fmaxf(mB, __shfl_xor(mB, 32));

        int dtot = degA + degB;
        float sA = 0.f, sB = 0.f;
        for (int i = j; i < dtot; i += 8) {
            bool isA = i < degA;
            float e = exp2f(wl[i * NHEAD + h] - (isA ? mA : mB));
            wl[i * NHEAD + h] = e;
            sA += isA ? e : 0.f;
            sB += isA ? 0.f : e;
        }
        sA += __shfl_xor(sA, 8);   sB += __shfl_xor(sB, 8);
        sA += __shfl_xor(sA, 16);  sB += __shfl_xor(sB, 16);
        sA += __shfl_xor(sA, 32);  sB += __shfl_xor(sB, 32);
        float siA = (sA > 0.f) ? 1.0f / sA : 0.f;
        float siB = (sB > 0.f) ? 1.0f / sB : 0.f;
        float siAh = __shfl(siA, hc);
        float siBh = __shfl(siB, hc);

        float accA0 = 0.f, accA1 = 0.f, accB0 = 0.f, accB1 = 0.f;
        int i = 0;
        for (; i + 4 <= degA; i += 4) {
            int oo0 = sl[i + 0], oo1 = sl[i + 1], oo2 = sl[i + 2], oo3 = sl[i + 3];
            unsigned int u0 = *(const unsigned int*)(vr1 + oo0 + 2 * lane);
            unsigned int u1 = *(const unsigned int*)(vr1 + oo1 + 2 * lane);
            unsigned int u2 = *(const unsigned int*)(vr1 + oo2 + 2 * lane);
            unsigned int u3 = *(const unsigned int*)(vr1 + oo3 + 2 * lane);
            float w0 = wl[(i + 0) * NHEAD + hc];
            float w1 = wl[(i + 1) * NHEAD + hc];
            float w2 = wl[(i + 2) * NHEAD + hc];
            float w3 = wl[(i + 3) * NHEAD + hc];
            float2 v0 = b2x2(u0), v1 = b2x2(u1), v2 = b2x2(u2), v3 = b2x2(u3);
            accA0 += w0 * v0.x + w1 * v1.x + w2 * v2.x + w3 * v3.x;
            accA1 += w0 * v0.y + w1 * v1.y + w2 * v2.y + w3 * v3.y;
        }
        for (; i < degA; i++) {
            int oo = sl[i];
            unsigned int u0 = *(const unsigned int*)(vr1 + oo + 2 * lane);
            float w0 = wl[i * NHEAD + hc];
            float2 v0 = b2x2(u0);
            accA0 += w0 * v0.x; accA1 += w0 * v0.y;
        }
        for (; i + 4 <= dtot; i += 4) {
            int oo0 = sl[i + 0], oo1 = sl[i + 1], oo2 = sl[i + 2], oo3 = sl[i + 3];
            unsigned int u0 = *(const unsigned int*)(vr1 + oo0 + 2 * lane);
            unsigned int u1 = *(const unsigned int*)(vr1 + oo1 + 2 * lane);
            unsigned int u2 = *(const unsigned int*)(vr1 + oo2 + 2 * lane);
            unsigned int u3 = *(const unsigned int*)(vr1 + oo3 + 2 * lane);
            float w0 = wl[(i + 0) * NHEAD + hc];
            float w1 = wl[(i + 1) * NHEAD + hc];
            float w2 = wl[(i + 2) * NHEAD + hc];
            float w3 = wl[(i + 3) * NHEAD + hc];
            float2 v0 = b2x2(u0), v1 = b2x2(u1), v2 = b2x2(u2), v3 = b2x2(u3);
            accB0 += w0 * v0.x + w1 * v1.x + w2 * v2.x + w3 * v3.x;
            accB1 += w0 * v0.y + w1 * v1.y + w2 * v2.y + w3 * v3.y;
        }
        for (; i < dtot; i++) {
            int oo = sl[i];
            unsigned int u0 = *(const unsigned int*)(vr1 + oo + 2 * lane);
            float w0 = wl[i * NHEAD + hc];
            float2 v0 = b2x2(u0);
            accB0 += w0 * v0.x; accB1 += w0 * v0.y;
        }
        o0 = accA0 * siAh + accB0 * siBh;
        o1 = accA1 * siAh + accB1 * siBh;
    } else {
        float acc0 = 0.f, acc1 = 0.f;
        #pragma unroll
        for (int rr = 0; rr < 2; rr++) {
            const unsigned int* es = rr ? es3 : es1;
            const unsigned short* kr = rr ? kr3 : kr1;
            const unsigned short* vr = rr ? vr3 : vr1;
            int ld = rr ? ld3 : ld1;
            const float* prel = rr ? prel3 : prel1;
            int r0 = rr ? r0b : r0a;
            int deg = rr ? degB : degA;
            if (deg <= 0) continue;
            const unsigned short* qrow = qbase + h * DHEAD;
            float ph = prel[h] * 0.25f * LOG2E;
            bool small = (deg <= 64);

            float m = -1e30f;
            for (int i = j; i < deg; i += 8) {
                int sn = es[r0 + i] >> 16;
                float a = dot16_bf(qrow, kr + (size_t)sn * ld + h * DHEAD) * ph;
                if (small) wl[i * NHEAD + h] = a;
                m = fmaxf(m, a);
            }
            m = fmaxf(m, __shfl_xor(m, 8));
            m = fmaxf(m, __shfl_xor(m, 16));
            m = fmaxf(m, __shfl_xor(m, 32));
            float s = 0.f;
            for (int i = j; i < deg; i += 8) {
                float a;
                if (small) a = wl[i * NHEAD + h];
                else {
                    int sn = es[r0 + i] >> 16;
                    a = dot16_bf(qrow, kr + (size_t)sn * ld + h * DHEAD) * ph;
                }
                float e = exp2f(a - m);
                if (small) wl[i * NHEAD + h] = e;
                s += e;
            }
            s += __shfl_xor(s, 8);
            s += __shfl_xor(s, 16);
            s += __shfl_xor(s, 32);
            float si = (s > 0.f) ? 1.0f / s : 0.f;
            if (small)
                for (int i = j; i < deg; i += 8)
                    wl[i * NHEAD + h] *= si;

            float m_hc  = __shfl(m, hc);
            float si_hc = __shfl(si, hc);
            float ph_hc = __shfl(ph, hc);
            const unsigned short* qrow_hc = qbase + hc * DHEAD;
            for (int i = 0; i < deg; i++) {
                unsigned int sv = es[r0 + i] >> 16;
                unsigned int pv = *(const unsigned int*)(vr + (size_t)sv * ld + 2 * lane);
                float2 v = b2x2(pv);
                float wgt;
                if (small) wgt = wl[i * NHEAD + hc];
                else {
                    float a = dot16_bf(qrow_hc, kr + (size_t)sv * ld + hc * DHEAD) * ph_hc;
                    wgt = exp2f(a - m_hc) * si_hc;
                }
                acc0 += wgt * v.x;
                acc1 += wgt * v.y;
            }
        }
        o0 = acc0; o1 = acc1;
    }
    unsigned int packed = (unsigned int)f2b(gelu_fast(o0))
                        | ((unsigned int)f2b(gelu_fast(o1)) << 16);
    *(unsigned int*)(agg + (size_t)wid * CDIM + 2 * lane) = packed;
}

// ---------------------------------------------------------------------------
extern "C" void kernel_launch(void* const* d_in, const int* in_sizes, int n_in,
                              void* d_out, int out_size, void* d_ws, size_t ws_size,
                              hipStream_t stream)
{
    const float* x_patient = (const float*)d_in[0];
    const float* w_in      = (const float*)d_in[1];
    const float* b_in      = (const float*)d_in[2];
    const float* emb_icd   = (const float*)d_in[3];
    const float* emb_ndc   = (const float*)d_in[4];
    const float* kw        = (const float*)d_in[5];
    const float* kbias     = (const float*)d_in[6];
    const float* qw        = (const float*)d_in[7];
    const float* qbias     = (const float*)d_in[8];
    const float* vw        = (const float*)d_in[9];
    const float* vbias     = (const float*)d_in[10];
    const float* aw        = (const float*)d_in[11];
    const float* abias     = (const float*)d_in[12];
    const float* skip      = (const float*)d_in[13];
    const float* a_rel     = (const float*)d_in[14];
    const float* m_rel     = (const float*)d_in[15];
    const float* p_rel     = (const float*)d_in[16];
    const float* w_out     = (const float*)d_in[17];
    const float* b_out     = (const float*)d_in[18];
    const int*   x_icd     = (const int*)d_in[19];
    const int*   x_ndc     = (const int*)d_in[20];
    const int* esrc[4] = {(const int*)d_in[21], (const int*)d_in[23],
                          (const int*)d_in[25], (const int*)d_in[27]};
    const int* edst[4] = {(const int*)d_in[22], (const int*)d_in[24],
                          (const int*)d_in[26], (const int*)d_in[28]};

    const int sizes[3] = {NPAT, NICD, NNDC};

    char* p = (char*)d_ws;
    auto alloc = [&](size_t bytes) -> void* {
        void* r = (void*)p;
        p += (bytes + 255) & ~(size_t)255;
        return r;
    };

    unsigned short *xb[3];
    for (int t = 0; t < 3; t++) xb[t] = (unsigned short*)alloc((size_t)sizes[t] * CDIM * 2);
    unsigned short* P0 = (unsigned short*)alloc((size_t)NPAT * 640 * 2);
    unsigned short* P1 = (unsigned short*)alloc((size_t)NICD * 384 * 2);
    unsigned short* P2 = (unsigned short*)alloc((size_t)NNDC * 384 * 2);
    unsigned short* aggbase = (unsigned short*)alloc((size_t)(NPAT + NICD + NNDC) * CDIM * 2);
    unsigned short* agg[3];
    agg[0] = aggbase;
    agg[1] = aggbase + (size_t)NPAT * CDIM;
    agg[2] = agg[1] + (size_t)NICD * CDIM;
    float*  alphabuf  = (float*)alloc((size_t)NEDGE * NHEAD * 4);
    float*  alphabuf2 = (float*)alloc((size_t)NEDGE * NHEAD * 4);
    unsigned int* esbig = (unsigned int*)alloc((size_t)4 * NEDGE * 4);
    int* rowptr[4];
    rowptr[0] = (int*)alloc((size_t)(NICD + 1) * 4);
    rowptr[1] = (int*)alloc((size_t)(NPAT + 1) * 4);
    rowptr[2] = (int*)alloc((size_t)(NNDC + 1) * 4);
    rowptr[3] = (int*)alloc((size_t)(NPAT + 1) * 4);
    int* deg    = (int*)alloc((size_t)NTOT * 4);
    int* cursor = (int*)alloc((size_t)NTOT * 4);
    int* part   = (int*)alloc((size_t)256 * 4);
    unsigned short* Wb0   = (unsigned short*)alloc((size_t)2 * 640 * 128 * 2);
    unsigned short* Wb1   = (unsigned short*)alloc((size_t)2 * 384 * 128 * 2);
    unsigned short* Wb2   = (unsigned short*)alloc((size_t)2 * 384 * 128 * 2);
    unsigned short* Wtaw  = (unsigned short*)alloc((size_t)6 * 128 * 128 * 2);
    unsigned short* Wtin  = (unsigned short*)alloc((size_t)128 * 128 * 2);
    unsigned short* Wtout = (unsigned short*)alloc((size_t)OUTN * 128 * 2);
    float* bb0 = (float*)alloc((size_t)2 * 640 * 4);
    float* bb1 = (float*)alloc((size_t)2 * 384 * 4);
    float* bb2 = (float*)alloc((size_t)2 * 384 * 4);
    unsigned int* esRel[4];
    for (int r = 0; r < 4; r++) esRel[r] = esbig + (size_t)r * NEDGE;

    // ---- 1: merged prep ----
    prep_all_kernel<<<dim3(PB_G), dim3(256), 0, stream>>>(
        qw, aw, w_in, w_out, Wb0, Wb1, Wb2, Wtaw, Wtin, Wtout,
        kw, vw, a_rel, m_rel, kbias, vbias, bb0, bb1, bb2, qbias,
        deg, emb_icd, x_icd, xb[1], emb_ndc, x_ndc, xb[2]);

    // ---- 2-4: CSR build ----
    hist4_kernel<<<dim3(256, 4), 256, 0, stream>>>(
        edst[0], edst[1], edst[2], edst[3], deg);
    scanA_kernel<<<NB_SCAN, 256, 0, stream>>>(deg, part, NTOT);
    scanC2_kernel<<<NB_SCAN, 256, 0, stream>>>(deg, part,
        rowptr[0], rowptr[1], rowptr[2], rowptr[3], cursor, NTOT);

    // ---- 5: scatter (2048 blocks) + input projection ----
    scat_in_kernel<<<dim3(SI_SCAT + SI_NWG), 256, 0, stream>>>(
        esrc[0], edst[0], esrc[1], edst[1], esrc[2], edst[2], esrc[3], edst[3],
        cursor, esbig, x_patient, Wtin, b_in, xb[0]);

    // GEMM3 geometry
    const int ntP0 = 640 / 64, nwgP0 = ((NPAT + 63) / 64) * ntP0;
    const int ntP1 = 384 / 64, nwgP1 = ((NICD + 63) / 64) * ntP1;
    const int ntP2 = 384 / 64, nwgP2 = ((NNDC + 63) / 64) * ntP2;
    const int ntS  = 128 / 64;
    const int nwgS0 = ((NPAT + 63) / 64) * ntS;
    const int nwgS1 = ((NICD + 63) / 64) * ntS;
    const int nwgS2 = ((NNDC + 63) / 64) * ntS;

    // ---- layers ----
    for (int l = 0; l < NLAYER; l++) {
        gemm3_kernel<<<dim3(nwgP0 + nwgP1 + nwgP2), dim3(256), 0, stream>>>(
            xb[0], Wb0 + (size_t)l * 640 * 128, bb0 + (size_t)l * 640, P0,
            NPAT, 640, ntP0, nwgP0,
            xb[1], Wb1 + (size_t)l * 384 * 128, bb1 + (size_t)l * 384, P1,
            NICD, 384, ntP1, nwgP0 + nwgP1,
            xb[2], Wb2 + (size_t)l * 384 * 128, bb2 + (size_t)l * 384, P2,
            NNDC, 384, ntP2,
            nullptr, 0, 0, 0);

        seg_kernel<<<dim3(NNDC, 2), dim3(256), 0, stream>>>(
            rowptr[0], esRel[0], P1, 384, P0 + 128, P0 + 256, 640,
            p_rel + (size_t)(l * 4 + 0) * NHEAD, alphabuf, agg[1], NICD,
            rowptr[2], esRel[2], P2, 384, P0 + 384, P0 + 512, 640,
            p_rel + (size_t)(l * 4 + 2) * NHEAD, alphabuf2, agg[2], NNDC);

        agg2_kernel<<<dim3(NAGG), dim3(256), 0, stream>>>(
            rowptr[1], esRel[1], rowptr[3], esRel[3],
            P0, 640, P1 + 128, P1 + 256, 384, P2 + 128, P2 + 256, 384,
            p_rel + (size_t)(l * 4 + 1) * NHEAD, p_rel + (size_t)(l * 4 + 3) * NHEAD,
            agg[0], NPAT);

        gemm3_kernel<<<dim3(nwgS0 + nwgS1 + nwgS2), dim3(256), 0, stream>>>(
            agg[0], Wtaw + (size_t)(l * 3 + 0) * 16384, abias + (size_t)(l * 3 + 0) * 128, xb[0],
            NPAT, 128, ntS, nwgS0,
            agg[1], Wtaw + (size_t)(l * 3 + 1) * 16384, abias + (size_t)(l * 3 + 1) * 128, xb[1],
            NICD, 128, ntS, nwgS0 + nwgS1,
            agg[2], Wtaw + (size_t)(l * 3 + 2) * 16384, abias + (size_t)(l * 3 + 2) * 128, xb[2],
            NNDC, 128, ntS,
            skip, l * 3 + 0, l * 3 + 1, l * 3 + 2);
    }

    // ---- output head (fp32 out) ----
    {
        int ntile = (OUTN + 63) / 64;
        int nwg = ((NPAT + 63) / 64) * ntile;
        gemm_xs<<<dim3(nwg), dim3(256), 0, stream>>>(xb[0], 0, 128, Wtout, b_out,
            d_out, 1, OUTN, NPAT, OUTN, 2, ntile, nullptr, 0, nullptr, 0);
    }
}

// Round 13
// 467.809 us; speedup vs baseline: 1.0833x; 1.0833x over previous
//
#include <hip/hip_runtime.h>
#include <math.h>

#define CDIM  128
#define NHEAD 8
#define DHEAD 16
#define NPAT  50000
#define NICD  591
#define NNDC  2042
#define OUTN  90
#define NEDGE 250000
#define NLAYER 2
#define ALC   640    // LDS-alpha fast-path degree cap (icd max deg ~500)

// concat offsets for CSR build (relation order: pi, ip, pn, np; dst sizes)
#define OFF0  0
#define OFF1  (NICD)
#define OFF2  (NICD + NPAT)
#define OFF3  (NICD + NPAT + NNDC)
#define NTOT  (NICD + NPAT + NNDC + NPAT)
#define NB_SCAN ((NTOT + 1023) / 1024)     // 101

#define LDP 40     // GEMM LDS row stride (bf16 elems)
#define CTILE 72   // GEMM epilogue staging row stride (bf16)
#define LOG2E 1.4426950408889634f

#define NSEG  (2 * NNDC)
#define NAGG  ((NPAT + 3) / 4)

// prep_all block ranges
#define PB_W  224                          // wprep (4*4*14)
#define PB_C  (PB_W + 16)                  // wcomp
#define PB_Q  (PB_C + 3)                   // biasq
#define PB_Z  (PB_Q + NB_SCAN)             // zero deg
#define PB_G  (PB_Z + (((NICD + NNDC) * CDIM + 255) / 256))  // gather

// scatter geometry (R11 proven: 64 blocks/relation)
#define SCAT_PER 64
#define SCAT_N   (4 * SCAT_PER)            // 256
#define INP_NWG  (((NPAT + 63) / 64) * 2)  // 1564 input-proj blocks

typedef __attribute__((ext_vector_type(8))) short bf16x8;
typedef __attribute__((ext_vector_type(4))) float f32x4;

__device__ __forceinline__ float gelu_fast(float x) {
    float x3 = x * x * x;
    float y = 0.7978845608028654f * (x + 0.044715f * x3);
    float e = exp2f(y * (2.0f * LOG2E));
    float t = 1.0f - 2.0f * __builtin_amdgcn_rcpf(e + 1.0f);
    return 0.5f * x * (1.0f + t);
}
__device__ __forceinline__ float b2f(unsigned short u) {
    union { unsigned int i; float f; } v; v.i = ((unsigned int)u) << 16; return v.f;
}
__device__ __forceinline__ unsigned short f2b(float f) {
    union { float ff; unsigned int i; } v; v.ff = f;
    unsigned int i = v.i;
    return (unsigned short)((i + 0x7FFFu + ((i >> 16) & 1u)) >> 16);  // RNE
}
__device__ __forceinline__ float2 b2x2(unsigned int u) {
    union { unsigned int i; float f; } lo, hi;
    lo.i = u << 16; hi.i = u & 0xFFFF0000u;
    return make_float2(lo.f, hi.f);
}

// ---------------------------------------------------------------------------
// Shared GEMM core (a_mode=0 bf16 A, c_mode=0 bf16 C, act=0, optional skip).
// ---------------------------------------------------------------------------
__device__ __forceinline__ void gemm_core(
    const unsigned short* __restrict__ Ap,
    const unsigned short* __restrict__ Wt, const float* __restrict__ bias,
    unsigned short* __restrict__ Cp, int ldc,
    int M, int N, int ntile, int wgid,
    const unsigned short* __restrict__ xold,
    const float* __restrict__ skipv, int skipidx,
    unsigned short* Al, unsigned short* Bl, unsigned short* Cst)
{
    int bm = (wgid / ntile) * 64, bn = (wgid % ntile) * 64;
    int t = threadIdx.x;
    int lane = t & 63, w = t >> 6;
    int wr = w >> 1, wc = w & 1;
    int quad = lane >> 4, lm = lane & 15;
    f32x4 acc[2][2] = {};
    const int srow = t >> 2;
    const int skq  = (t & 3) * 8;

    for (int k0 = 0; k0 < 128; k0 += 32) {
        {
            int row = bm + srow;
            uint4 u = make_uint4(0, 0, 0, 0);
            if (row < M)
                u = *(const uint4*)(Ap + (size_t)row * 128 + k0 + skq);
            *(uint4*)&Al[srow * LDP + skq] = u;
        }
        {
            int n = bn + srow;
            uint4 u = make_uint4(0, 0, 0, 0);
            if (n < N) u = *(const uint4*)(Wt + (size_t)n * 128 + k0 + skq);
            *(uint4*)&Bl[srow * LDP + skq] = u;
        }
        __syncthreads();
        bf16x8 af[2], bfr[2];
        #pragma unroll
        for (int i = 0; i < 2; i++) {
            af[i]  = *(const bf16x8*)&Al[(wr * 32 + i * 16 + lm) * LDP + quad * 8];
            bfr[i] = *(const bf16x8*)&Bl[(wc * 32 + i * 16 + lm) * LDP + quad * 8];
        }
        acc[0][0] = __builtin_amdgcn_mfma_f32_16x16x32_bf16(af[0], bfr[0], acc[0][0], 0, 0, 0);
        acc[0][1] = __builtin_amdgcn_mfma_f32_16x16x32_bf16(af[0], bfr[1], acc[0][1], 0, 0, 0);
        acc[1][0] = __builtin_amdgcn_mfma_f32_16x16x32_bf16(af[1], bfr[0], acc[1][0], 0, 0, 0);
        acc[1][1] = __builtin_amdgcn_mfma_f32_16x16x32_bf16(af[1], bfr[1], acc[1][1], 0, 0, 0);
        __syncthreads();
    }

    float aSk = 0.f, oneM = 0.f;
    if (skipv) {
        float sv = skipv[skipidx];
        aSk = 1.0f / (1.0f + expf(-sv));
        oneM = 1.0f - aSk;
    }
    #pragma unroll
    for (int tm = 0; tm < 2; tm++)
    #pragma unroll
    for (int tn = 0; tn < 2; tn++)
    #pragma unroll
    for (int r = 0; r < 4; r++) {
        int lrow = wr * 32 + tm * 16 + quad * 4 + r;
        int lcol = wc * 32 + tn * 16 + lm;
        int row = bm + lrow, col = bn + lcol;
        float v = acc[tm][tn][r] + (bias ? bias[col] : 0.f);
        if (skipv && row < M) v = aSk * v + oneM * b2f(xold[(size_t)row * ldc + col]);
        Cst[lrow * CTILE + lcol] = f2b(v);
    }
    __syncthreads();
    int row = t >> 2, seg = (t & 3) * 16;
    if (bm + row < M) {
        unsigned short* dst = Cp + (size_t)(bm + row) * ldc + bn + seg;
        *(uint4*)dst       = *(const uint4*)&Cst[row * CTILE + seg];
        *(uint4*)(dst + 8) = *(const uint4*)&Cst[row * CTILE + seg + 8];
    }
}

// triple-GEMM block dispatch (desc0 XCD-swizzled), local block index g
__device__ __forceinline__ void gemm3_body(
    int g,
    const unsigned short* A0, const unsigned short* W0,
    const float* b0, unsigned short* C0, int M0, int N0, int ntile0, int nwg0,
    const unsigned short* A1, const unsigned short* W1,
    const float* b1, unsigned short* C1, int M1, int N1, int ntile1, int nwg01,
    const unsigned short* A2, const unsigned short* W2,
    const float* b2, unsigned short* C2, int M2, int N2, int ntile2,
    const float* skipv, int si0, int si1, int si2,
    unsigned short* Al, unsigned short* Bl, unsigned short* Cst)
{
    if (g < nwg0) {
        int qq = nwg0 >> 3, rr = nwg0 & 7;
        int xcd = g & 7, idx = g >> 3;
        int wgid = (xcd < rr ? xcd * (qq + 1) : rr * (qq + 1) + (xcd - rr) * qq) + idx;
        gemm_core(A0, W0, b0, C0, N0, M0, N0, ntile0, wgid, C0, skipv, si0, Al, Bl, Cst);
    } else if (g < nwg01) {
        gemm_core(A1, W1, b1, C1, N1, M1, N1, ntile1, g - nwg0, C1, skipv, si1, Al, Bl, Cst);
    } else {
        gemm_core(A2, W2, b2, C2, N2, M2, N2, ntile2, g - nwg01, C2, skipv, si2, Al, Bl, Cst);
    }
}

__global__ __launch_bounds__(256) void gemm3_kernel(
    const unsigned short* __restrict__ A0, const unsigned short* __restrict__ W0,
    const float* __restrict__ b0, unsigned short* __restrict__ C0,
    int M0, int N0, int ntile0, int nwg0,
    const unsigned short* __restrict__ A1, const unsigned short* __restrict__ W1,
    const float* __restrict__ b1, unsigned short* __restrict__ C1,
    int M1, int N1, int ntile1, int nwg01,
    const unsigned short* __restrict__ A2, const unsigned short* __restrict__ W2,
    const float* __restrict__ b2, unsigned short* __restrict__ C2,
    int M2, int N2, int ntile2,
    const float* __restrict__ skipv, int si0, int si1, int si2)
{
    __shared__ unsigned short Al[64 * LDP];
    __shared__ unsigned short Bl[64 * LDP];
    __shared__ unsigned short Cst[64 * CTILE];
    gemm3_body(blockIdx.x, A0, W0, b0, C0, M0, N0, ntile0, nwg0,
               A1, W1, b1, C1, M1, N1, ntile1, nwg01,
               A2, W2, b2, C2, M2, N2, ntile2,
               skipv, si0, si1, si2, Al, Bl, Cst);
}

// ---------------------------------------------------------------------------
// input-projection GEMM body (fp32 A, relu, bf16 C), u = local block idx
// ---------------------------------------------------------------------------
__device__ __forceinline__ void input_proj_body(
    int u, char* smem,
    const float* __restrict__ Axp, const unsigned short* __restrict__ Wtin,
    const float* __restrict__ b_in, unsigned short* __restrict__ xb0)
{
    unsigned short* Al = (unsigned short*)smem;
    unsigned short* Bl = Al + 64 * LDP;
    unsigned short* Cst = Bl + 64 * LDP;
    int t = threadIdx.x;
    int nwg = INP_NWG;
    int qq = nwg >> 3, rr = nwg & 7;
    int xcd = u & 7, idx = u >> 3;
    int wgid = (xcd < rr ? xcd * (qq + 1) : rr * (qq + 1) + (xcd - rr) * qq) + idx;
    int bm = (wgid >> 1) * 64, bn = (wgid & 1) * 64;

    int lane = t & 63, w = t >> 6;
    int wr = w >> 1, wc = w & 1;
    int quad = lane >> 4, lm = lane & 15;
    f32x4 acc[2][2] = {};
    const int srow = t >> 2;
    const int skq  = (t & 3) * 8;

    for (int k0 = 0; k0 < 128; k0 += 32) {
        {
            int row = bm + srow;
            float f[8] = {0.f,0.f,0.f,0.f,0.f,0.f,0.f,0.f};
            if (row < NPAT) {
                const float4* ap = (const float4*)(Axp + (size_t)row * 128 + k0 + skq);
                float4 u0 = ap[0], u1 = ap[1];
                f[0]=u0.x; f[1]=u0.y; f[2]=u0.z; f[3]=u0.w;
                f[4]=u1.x; f[5]=u1.y; f[6]=u1.z; f[7]=u1.w;
            }
            unsigned short v[8];
            for (int i = 0; i < 8; i++) v[i] = f2b(f[i]);
            *(uint4*)&Al[srow * LDP + skq] = *(uint4*)v;
        }
        {
            int n = bn + srow;
            *(uint4*)&Bl[srow * LDP + skq] = *(const uint4*)(Wtin + (size_t)n * 128 + k0 + skq);
        }
        __syncthreads();
        bf16x8 af[2], bfr[2];
        #pragma unroll
        for (int i = 0; i < 2; i++) {
            af[i]  = *(const bf16x8*)&Al[(wr * 32 + i * 16 + lm) * LDP + quad * 8];
            bfr[i] = *(const bf16x8*)&Bl[(wc * 32 + i * 16 + lm) * LDP + quad * 8];
        }
        acc[0][0] = __builtin_amdgcn_mfma_f32_16x16x32_bf16(af[0], bfr[0], acc[0][0], 0, 0, 0);
        acc[0][1] = __builtin_amdgcn_mfma_f32_16x16x32_bf16(af[0], bfr[1], acc[0][1], 0, 0, 0);
        acc[1][0] = __builtin_amdgcn_mfma_f32_16x16x32_bf16(af[1], bfr[0], acc[1][0], 0, 0, 0);
        acc[1][1] = __builtin_amdgcn_mfma_f32_16x16x32_bf16(af[1], bfr[1], acc[1][1], 0, 0, 0);
        __syncthreads();
    }
    #pragma unroll
    for (int tm = 0; tm < 2; tm++)
    #pragma unroll
    for (int tn = 0; tn < 2; tn++)
    #pragma unroll
    for (int r = 0; r < 4; r++) {
        int lrow = wr * 32 + tm * 16 + quad * 4 + r;
        int lcol = wc * 32 + tn * 16 + lm;
        float v = acc[tm][tn][r] + b_in[bn + lcol];
        v = fmaxf(v, 0.f);
        Cst[lrow * CTILE + lcol] = f2b(v);
    }
    __syncthreads();
    int row = t >> 2, seg = (t & 3) * 16;
    if (bm + row < NPAT) {
        unsigned short* dst = xb0 + (size_t)(bm + row) * 128 + bn + seg;
        *(uint4*)dst       = *(const uint4*)&Cst[row * CTILE + seg];
        *(uint4*)(dst + 8) = *(const uint4*)&Cst[row * CTILE + seg + 8];
    }
}

// ---------------------------------------------------------------------------
// scatter body, b in [0, SCAT_N): rel = b / SCAT_PER, chunk = b % SCAT_PER
// ---------------------------------------------------------------------------
__device__ __forceinline__ void scatter_body(
    int b, char* smem,
    const int* s0, const int* d0, const int* s1, const int* d1,
    const int* s2, const int* d2, const int* s3, const int* d3,
    int* cursor, unsigned int* es)
{
    int t = threadIdx.x;
    int* lcnt = (int*)smem;
    int* lbase = lcnt + 2048;
    int rel = b / SCAT_PER;
    int bx = b % SCAT_PER;
    const int* sp = (rel == 0) ? s0 : (rel == 1) ? s1 : (rel == 2) ? s2 : s3;
    const int* dp = (rel == 0) ? d0 : (rel == 1) ? d1 : (rel == 2) ? d2 : d3;
    int off = (rel == 0) ? OFF0 : (rel == 1) ? OFF1 : (rel == 2) ? OFF2 : OFF3;
    if (rel == 1 || rel == 3) {
        for (int e = bx * 256 + t; e < NEDGE; e += SCAT_PER * 256) {
            int d = dp[e];
            int p = atomicAdd(&cursor[off + d], 1);
            es[p] = ((unsigned int)sp[e] << 16) | (unsigned int)d;
        }
    } else {
        int nb = (rel == 0) ? NICD : NNDC;
        int per = (NEDGE + SCAT_PER - 1) / SCAT_PER;
        int e0 = bx * per, e1 = min(e0 + per, NEDGE);
        for (int i = t; i < nb; i += 256) lcnt[i] = 0;
        __syncthreads();
        for (int e = e0 + t; e < e1; e += 256) atomicAdd(&lcnt[dp[e]], 1);
        __syncthreads();
        for (int i = t; i < nb; i += 256) {
            int c = lcnt[i];
            lbase[i] = c ? atomicAdd(&cursor[off + i], c) : 0;
            lcnt[i] = 0;
        }
        __syncthreads();
        for (int e = e0 + t; e < e1; e += 256) {
            int d = dp[e];
            int p = lbase[d] + atomicAdd(&lcnt[d], 1);
            es[p] = ((unsigned int)sp[e] << 16) | (unsigned int)d;
        }
    }
}

// ---------------------------------------------------------------------------
// MERGED hist4 + input-projection GEMM (independent work).
// blocks [0,256): hist4 (rel = b>>6, chunk = b&63); [256,256+INP_NWG): inproj.
// ---------------------------------------------------------------------------
__global__ __launch_bounds__(256) void hist_in_kernel(
    const int* __restrict__ d0, const int* __restrict__ d1,
    const int* __restrict__ d2, const int* __restrict__ d3,
    int* __restrict__ deg,
    const float* __restrict__ Axp, const unsigned short* __restrict__ Wtin,
    const float* __restrict__ b_in, unsigned short* __restrict__ xb0)
{
    __shared__ __align__(16) char smem[19456];
    int b = blockIdx.x;
    int t = threadIdx.x;
    if (b < 256) {
        int* lh = (int*)smem;
        int rel = b >> 6;
        int bx = b & 63;
        const int* dp = (rel == 0) ? d0 : (rel == 1) ? d1 : (rel == 2) ? d2 : d3;
        int off = (rel == 0) ? OFF0 : (rel == 1) ? OFF1 : (rel == 2) ? OFF2 : OFF3;
        if (rel == 1 || rel == 3) {
            for (int e = bx * 256 + t; e < NEDGE; e += 64 * 256)
                atomicAdd(&deg[off + dp[e]], 1);
        } else {
            int nb = (rel == 0) ? NICD : NNDC;
            for (int i = t; i < nb; i += 256) lh[i] = 0;
            __syncthreads();
            for (int e = bx * 256 + t; e < NEDGE; e += 64 * 256)
                atomicAdd(&lh[dp[e]], 1);
            __syncthreads();
            for (int i = t; i < nb; i += 256) {
                int v = lh[i];
                if (v) atomicAdd(&deg[off + i], v);
            }
        }
    } else {
        input_proj_body(b - 256, smem, Axp, Wtin, b_in, xb0);
    }
}

// ---------------------------------------------------------------------------
// MERGED scatter + layer-0 projection triple-GEMM (independent work).
// blocks [0, SCAT_N): scatter; rest: proj gemm3 (local idx b - SCAT_N).
// ---------------------------------------------------------------------------
__global__ __launch_bounds__(256) void scat_proj_kernel(
    const int* __restrict__ s0, const int* __restrict__ d0,
    const int* __restrict__ s1, const int* __restrict__ d1,
    const int* __restrict__ s2, const int* __restrict__ d2,
    const int* __restrict__ s3, const int* __restrict__ d3,
    int* __restrict__ cursor, unsigned int* __restrict__ es,
    const unsigned short* __restrict__ A0, const unsigned short* __restrict__ W0,
    const float* __restrict__ b0, unsigned short* __restrict__ C0,
    int M0, int N0, int ntile0, int nwg0,
    const unsigned short* __restrict__ A1, const unsigned short* __restrict__ W1,
    const float* __restrict__ b1, unsigned short* __restrict__ C1,
    int M1, int N1, int ntile1, int nwg01,
    const unsigned short* __restrict__ A2, const unsigned short* __restrict__ W2,
    const float* __restrict__ b2, unsigned short* __restrict__ C2,
    int M2, int N2, int ntile2)
{
    __shared__ __align__(16) char smem[19456];
    int b = blockIdx.x;
    if (b < SCAT_N) {
        scatter_body(b, smem, s0, d0, s1, d1, s2, d2, s3, d3, cursor, es);
    } else {
        unsigned short* Al = (unsigned short*)smem;
        unsigned short* Bl = Al + 64 * LDP;
        unsigned short* Cst = Bl + 64 * LDP;
        gemm3_body(b - SCAT_N, A0, W0, b0, C0, M0, N0, ntile0, nwg0,
                   A1, W1, b1, C1, M1, N1, ntile1, nwg01,
                   A2, W2, b2, C2, M2, N2, ntile2,
                   nullptr, 0, 0, 0, Al, Bl, Cst);
    }
}

// ---------------------------------------------------------------------------
// General bf16 MFMA GEMM — used only for the output head (c_mode 1 sigmoid).
// ---------------------------------------------------------------------------
__global__ __launch_bounds__(256) void gemm_xs(
    const void* __restrict__ Ap, int a_mode, int lda,
    const unsigned short* __restrict__ Wt, const float* __restrict__ bias,
    void* __restrict__ Cp, int c_mode, int ldc,
    int M, int N, int act, int ntile,
    const unsigned short* __restrict__ xold, int ldx,
    const float* __restrict__ skipv, int skipidx)
{
    __shared__ unsigned short Al[64 * LDP];
    __shared__ unsigned short Bl[64 * LDP];
    __shared__ unsigned short Cst[64 * CTILE];
    int nwg = gridDim.x;
    int orig = blockIdx.x;
    int qq = nwg >> 3, rr = nwg & 7;
    int xcd = orig & 7, idx = orig >> 3;
    int wgid = (xcd < rr ? xcd * (qq + 1) : rr * (qq + 1) + (xcd - rr) * qq) + idx;
    int bm = (wgid / ntile) * 64, bn = (wgid % ntile) * 64;

    int t = threadIdx.x;
    int lane = t & 63, w = t >> 6;
    int wr = w >> 1, wc = w & 1;
    int quad = lane >> 4, lm = lane & 15;
    f32x4 acc[2][2] = {};
    const int srow = t >> 2;
    const int skq  = (t & 3) * 8;

    for (int k0 = 0; k0 < 128; k0 += 32) {
        {
            int row = bm + srow;
            uint4 u = make_uint4(0, 0, 0, 0);
            if (a_mode == 0) {
                if (row < M)
                    u = *(const uint4*)((const unsigned short*)Ap + (size_t)row * lda + k0 + skq);
            } else {
                float f[8] = {0.f,0.f,0.f,0.f,0.f,0.f,0.f,0.f};
                if (row < M) {
                    const float4* ap = (const float4*)((const float*)Ap + (size_t)row * lda + k0 + skq);
                    float4 u0 = ap[0], u1 = ap[1];
                    f[0]=u0.x; f[1]=u0.y; f[2]=u0.z; f[3]=u0.w;
                    f[4]=u1.x; f[5]=u1.y; f[6]=u1.z; f[7]=u1.w;
                }
                unsigned short v[8];
                for (int i = 0; i < 8; i++) v[i] = f2b(f[i]);
                u = *(uint4*)v;
            }
            *(uint4*)&Al[srow * LDP + skq] = u;
        }
        {
            int n = bn + srow;
            uint4 u = make_uint4(0, 0, 0, 0);
            if (n < N) u = *(const uint4*)(Wt + (size_t)n * 128 + k0 + skq);
            *(uint4*)&Bl[srow * LDP + skq] = u;
        }
        __syncthreads();
        bf16x8 af[2], bfr[2];
        #pragma unroll
        for (int i = 0; i < 2; i++) {
            af[i]  = *(const bf16x8*)&Al[(wr * 32 + i * 16 + lm) * LDP + quad * 8];
            bfr[i] = *(const bf16x8*)&Bl[(wc * 32 + i * 16 + lm) * LDP + quad * 8];
        }
        acc[0][0] = __builtin_amdgcn_mfma_f32_16x16x32_bf16(af[0], bfr[0], acc[0][0], 0, 0, 0);
        acc[0][1] = __builtin_amdgcn_mfma_f32_16x16x32_bf16(af[0], bfr[1], acc[0][1], 0, 0, 0);
        acc[1][0] = __builtin_amdgcn_mfma_f32_16x16x32_bf16(af[1], bfr[0], acc[1][0], 0, 0, 0);
        acc[1][1] = __builtin_amdgcn_mfma_f32_16x16x32_bf16(af[1], bfr[1], acc[1][1], 0, 0, 0);
        __syncthreads();
    }

    if (c_mode == 0) {
        #pragma unroll
        for (int tm = 0; tm < 2; tm++)
        #pragma unroll
        for (int tn = 0; tn < 2; tn++)
        #pragma unroll
        for (int r = 0; r < 4; r++) {
            int lrow = wr * 32 + tm * 16 + quad * 4 + r;
            int lcol = wc * 32 + tn * 16 + lm;
            int col = bn + lcol;
            float v = acc[tm][tn][r] + (bias ? bias[col] : 0.f);
            if (act == 1) v = fmaxf(v, 0.f);
            Cst[lrow * CTILE + lcol] = f2b(v);
        }
        __syncthreads();
        int row = t >> 2, seg = (t & 3) * 16;
        if (bm + row < M) {
            unsigned short* dst = (unsigned short*)Cp + (size_t)(bm + row) * ldc + bn + seg;
            *(uint4*)dst       = *(const uint4*)&Cst[row * CTILE + seg];
            *(uint4*)(dst + 8) = *(const uint4*)&Cst[row * CTILE + seg + 8];
        }
    } else {
        #pragma unroll
        for (int tm = 0; tm < 2; tm++)
        #pragma unroll
        for (int tn = 0; tn < 2; tn++)
        #pragma unroll
        for (int r = 0; r < 4; r++) {
            int row = bm + wr * 32 + tm * 16 + quad * 4 + r;
            int col = bn + wc * 32 + tn * 16 + lm;
            if (row >= M || col >= N) continue;
            float v = acc[tm][tn][r] + (bias ? bias[col] : 0.f);
            if (act == 1) v = fmaxf(v, 0.f);
            else if (act == 2) v = 1.0f / (1.0f + expf(-v));
            ((float*)Cp)[(size_t)row * ldc + col] = v;
        }
    }
}

// ---------------------------------------------------------------------------
// MERGED prep: wprep + wcomp + biasq + deg zeroing + embedding gathers.
// ---------------------------------------------------------------------------
__global__ __launch_bounds__(256) void prep_all_kernel(
    const float* __restrict__ qw, const float* __restrict__ aw,
    const float* __restrict__ w_in, const float* __restrict__ w_out,
    unsigned short* __restrict__ Wb0, unsigned short* __restrict__ Wb1,
    unsigned short* __restrict__ Wb2, unsigned short* __restrict__ Wtaw,
    unsigned short* __restrict__ Wtin, unsigned short* __restrict__ Wtout,
    const float* __restrict__ kw, const float* __restrict__ vw,
    const float* __restrict__ a_rel, const float* __restrict__ m_rel,
    const float* __restrict__ kb, const float* __restrict__ vb,
    float* __restrict__ bb0, float* __restrict__ bb1, float* __restrict__ bb2,
    const float* __restrict__ qb,
    int* __restrict__ deg,
    const float* __restrict__ emb_icd, const int* __restrict__ x_icd,
    unsigned short* __restrict__ xb1,
    const float* __restrict__ emb_ndc, const int* __restrict__ x_ndc,
    unsigned short* __restrict__ xb2)
{
    __shared__ float tile[32][33];
    int b = blockIdx.x;
    int tid = threadIdx.x;
    if (b < PB_W) {
        int z = b >> 4, rem = b & 15;
        int by = rem >> 2, bx = rem & 3;
        const float* s; unsigned short* d; int N = 128;
        if (z < 2)       { s = qw + (size_t)z * 3 * 16384;               d = Wb0 + (size_t)z * 640 * 128; }
        else if (z < 4)  { s = qw + 16384 + (size_t)(z - 2) * 3 * 16384; d = Wb1 + (size_t)(z - 2) * 384 * 128; }
        else if (z < 6)  { s = qw + 2 * 16384 + (size_t)(z - 4) * 3 * 16384; d = Wb2 + (size_t)(z - 4) * 384 * 128; }
        else if (z < 12) { s = aw + (size_t)(z - 6) * 16384;             d = Wtaw + (size_t)(z - 6) * 16384; }
        else if (z == 12){ s = w_in;  d = Wtin; }
        else             { s = w_out; d = Wtout; N = OUTN; }
        int k0 = bx * 32, n0 = by * 32;
        int tx = tid & 31, ty = tid >> 5;
        for (int i = 0; i < 32; i += 8) {
            int k = k0 + ty + i, n = n0 + tx;
            tile[ty + i][tx] = (k < 128 && n < N) ? s[(size_t)k * N + n] : 0.f;
        }
        __syncthreads();
        for (int i = 0; i < 32; i += 8) {
            int n = n0 + ty + i, k = k0 + tx;
            if (n < N && k < 128) d[(size_t)n * 128 + k] = f2b(tile[tx][ty + i]);
        }
    } else if (b < PB_C) {
        int s = b - PB_W;
        int l = s >> 3, j = s & 7;
        int ty, isV, r, rowoff, nw;
        unsigned short* Wb; float* bb;
        switch (j) {
          case 0: ty=0; isV=0; r=0; Wb=Wb0; bb=bb0; rowoff=128; nw=640; break;
          case 1: ty=0; isV=1; r=0; Wb=Wb0; bb=bb0; rowoff=256; nw=640; break;
          case 2: ty=0; isV=0; r=2; Wb=Wb0; bb=bb0; rowoff=384; nw=640; break;
          case 3: ty=0; isV=1; r=2; Wb=Wb0; bb=bb0; rowoff=512; nw=640; break;
          case 4: ty=1; isV=0; r=1; Wb=Wb1; bb=bb1; rowoff=128; nw=384; break;
          case 5: ty=1; isV=1; r=1; Wb=Wb1; bb=bb1; rowoff=256; nw=384; break;
          case 6: ty=2; isV=0; r=3; Wb=Wb2; bb=bb2; rowoff=128; nw=384; break;
          default:ty=2; isV=1; r=3; Wb=Wb2; bb=bb2; rowoff=256; nw=384; break;
        }
        const float* W = (isV ? vw : kw) + (size_t)(l * 3 + ty) * 16384;
        const float* A = (isV ? m_rel : a_rel) + (size_t)(l * 4 + r) * 2048;
        const float* B = (isV ? vb : kb) + (size_t)(l * 3 + ty) * 128;
        unsigned short* dst = Wb + (size_t)l * nw * 128 + (size_t)rowoff * 128;
        float* bdst = bb + (size_t)l * nw + rowoff;
        int n = tid & 127;
        int kh = tid >> 7;
        int h = n >> 4, e = n & 15;
        float Ar[16];
        #pragma unroll
        for (int d = 0; d < 16; d++) Ar[d] = A[h * 256 + d * 16 + e];
        for (int k = kh * 64; k < kh * 64 + 64; k++) {
            float acc = 0.f;
            const float* wr = W + (size_t)k * 128 + h * 16;
            #pragma unroll
            for (int d = 0; d < 16; d++) acc += wr[d] * Ar[d];
            dst[(size_t)n * 128 + k] = f2b(acc);
        }
        if (kh == 0) {
            float acc = 0.f;
            const float* br = B + h * 16;
            #pragma unroll
            for (int d = 0; d < 16; d++) acc += br[d] * Ar[d];
            bdst[n] = acc;
        }
    } else if (b < PB_Q) {
        int t = (b - PB_C) * 256 + tid;
        if (t < 6 * 128) {
            int g = t >> 7, c = t & 127;
            int l = g / 3, ty = g % 3;
            float v = qb[g * 128 + c];
            if (ty == 0) bb0[l * 640 + c] = v;
            else if (ty == 1) bb1[l * 384 + c] = v;
            else bb2[l * 384 + c] = v;
        }
    } else if (b < PB_Z) {
        int base = (b - PB_Q) * 1024 + tid * 4;
        if (base + 3 < NTOT) *(int4*)(deg + base) = make_int4(0, 0, 0, 0);
        else for (int i = 0; i < 4; i++) if (base + i < NTOT) deg[base + i] = 0;
    } else {
        int t = (b - PB_Z) * 256 + tid;
        int totA = NICD * CDIM;
        if (t < totA) {
            int r = t >> 7, c = t & 127;
            xb1[t] = f2b(fmaxf(emb_icd[(size_t)x_icd[r] * CDIM + c], 0.f));
        } else if (t < totA + NNDC * CDIM) {
            int u = t - totA;
            int r = u >> 7, c = u & 127;
            xb2[u] = f2b(fmaxf(emb_ndc[(size_t)x_ndc[r] * CDIM + c], 0.f));
        }
    }
}

__global__ __launch_bounds__(256) void scanA_kernel(
    const int* __restrict__ deg, int* __restrict__ part, int n)
{
    __shared__ int red[256];
    int b = blockIdx.x, t = threadIdx.x;
    int base = b * 1024 + t * 4;
    int s = 0;
    if (base + 3 < n) {
        int4 v = *(const int4*)(deg + base);
        s = v.x + v.y + v.z + v.w;
    } else {
        for (int i = 0; i < 4; i++) if (base + i < n) s += deg[base + i];
    }
    red[t] = s;
    __syncthreads();
    for (int o = 128; o; o >>= 1) { if (t < o) red[t] += red[t + o]; __syncthreads(); }
    if (t == 0) part[b] = red[0];
}

// scanC2: includes inline prefix-of-part (replaces scanB dispatch)
__global__ __launch_bounds__(256) void scanC2_kernel(
    const int* __restrict__ deg, const int* __restrict__ part,
    int* __restrict__ rp0, int* __restrict__ rp1,
    int* __restrict__ rp2, int* __restrict__ rp3,
    int* __restrict__ cursor, int n)
{
    __shared__ int red[256];
    __shared__ int pre[128];
    int b = blockIdx.x, t = threadIdx.x;
    if (t < 128) pre[t] = (t < b) ? part[t] : 0;
    __syncthreads();
    for (int o = 64; o; o >>= 1) { if (t < o) pre[t] += pre[t + o]; __syncthreads(); }
    int pbase = pre[0];
    __syncthreads();

    int base = b * 1024 + t * 4;
    int v[4] = {0, 0, 0, 0};
    if (base + 3 < n) {
        int4 q = *(const int4*)(deg + base);
        v[0] = q.x; v[1] = q.y; v[2] = q.z; v[3] = q.w;
    } else {
        for (int i = 0; i < 4; i++) if (base + i < n) v[i] = deg[base + i];
    }
    red[t] = v[0] + v[1] + v[2] + v[3];
    __syncthreads();
    for (int off = 1; off < 256; off <<= 1) {
        int y = (t >= off) ? red[t - off] : 0;
        __syncthreads();
        red[t] += y;
        __syncthreads();
    }
    int run = pbase + ((t == 0) ? 0 : red[t - 1]);
    for (int i = 0; i < 4; i++) {
        int g = base + i;
        if (g < n) {
            cursor[g] = run;
            int r, loc;
            if      (g < OFF1) { r = 0; loc = g; }
            else if (g < OFF2) { r = 1; loc = g - OFF1; }
            else if (g < OFF3) { r = 2; loc = g - OFF2; }
            else               { r = 3; loc = g - OFF3; }
            int Sl = run - r * NEDGE;
            ((r == 0) ? rp0 : (r == 1) ? rp1 : (r == 2) ? rp2 : rp3)[loc] = Sl;
            run += v[i];
        }
    }
    if (b == 0 && t == 0) {
        rp0[NICD] = NEDGE; rp1[NPAT] = NEDGE; rp2[NNDC] = NEDGE; rp3[NPAT] = NEDGE;
    }
}

__device__ __forceinline__ float dot16_bf(const unsigned short* a,
                                          const unsigned short* b) {
    const uint4* ap = (const uint4*)a;
    const uint4* bp = (const uint4*)b;
    uint4 a0 = ap[0], a1 = ap[1], b0 = bp[0], b1 = bp[1];
    unsigned int au[8] = {a0.x, a0.y, a0.z, a0.w, a1.x, a1.y, a1.z, a1.w};
    unsigned int bu[8] = {b0.x, b0.y, b0.z, b0.w, b1.x, b1.y, b1.z, b1.w};
    float acc = 0.f;
    #pragma unroll
    for (int j = 0; j < 8; j++) {
        float2 x = b2x2(au[j]), y = b2x2(bu[j]);
        acc += x.x * y.x + x.y * y.y;
    }
    return acc;
}

__device__ __forceinline__ float dot16_q(uint4 a0, uint4 a1,
                                         const unsigned short* b) {
    const uint4* bp = (const uint4*)b;
    uint4 b0 = bp[0], b1 = bp[1];
    unsigned int au[8] = {a0.x, a0.y, a0.z, a0.w, a1.x, a1.y, a1.z, a1.w};
    unsigned int bu[8] = {b0.x, b0.y, b0.z, b0.w, b1.x, b1.y, b1.z, b1.w};
    float acc = 0.f;
    #pragma unroll
    for (int j = 0; j < 8; j++) {
        float2 x = b2x2(au[j]), y = b2x2(bu[j]);
        acc += x.x * y.x + x.y * y.y;
    }
    return acc;
}

// ---------------------------------------------------------------------------
// seg kernel (icd/ndc-dst), one workgroup per dst node, grid.y = relation.
// ---------------------------------------------------------------------------
__global__ __launch_bounds__(256) void seg_kernel(
    const int* __restrict__ rpA, const unsigned int* __restrict__ esA,
    const unsigned short* __restrict__ qA, int ldqA,
    const unsigned short* __restrict__ krA, const unsigned short* __restrict__ vrA, int ldsA,
    const float* __restrict__ prelA, float* __restrict__ alphaA,
    unsigned short* __restrict__ aggA, int ndA,
    const int* __restrict__ rpB, const unsigned int* __restrict__ esB,
    const unsigned short* __restrict__ qB, int ldqB,
    const unsigned short* __restrict__ krB, const unsigned short* __restrict__ vrB, int ldsB,
    const float* __restrict__ prelB, float* __restrict__ alphaB,
    unsigned short* __restrict__ aggB, int ndB)
{
    __shared__ float wred[4][8];
    __shared__ float sinv[8];
    __shared__ float p3f[4][64][2];
    __shared__ float wl[ALC * NHEAD];
    __shared__ unsigned short sl[ALC];
    int rel = blockIdx.y;
    int n = blockIdx.x;
    const int* rp            = rel ? rpB : rpA;
    const unsigned int* es   = rel ? esB : esA;
    const unsigned short* q  = rel ? qB : qA;
    int ldq                  = rel ? ldqB : ldqA;
    const unsigned short* kr = rel ? krB : krA;
    const unsigned short* vr = rel ? vrB : vrA;
    int ldsrc                = rel ? ldsB : ldsA;
    const float* prel        = rel ? prelB : prelA;
    float* alpha             = rel ? alphaB : alphaA;
    unsigned short* agg      = rel ? aggB : aggA;
    int nd                   = rel ? ndB : ndA;
    if (n >= nd) return;

    int r0 = rp[n], deg = rp[n + 1] - r0;
    int t = threadIdx.x;
    int h = t & 7, j = t >> 3;
    int lane = t & 63, wv = t >> 6;
    const unsigned short* qrow = q + (size_t)n * ldq + h * DHEAD;
    uint4 qa = ((const uint4*)qrow)[0], qb = ((const uint4*)qrow)[1];
    float ph = prel[h] * 0.25f * LOG2E;

    if (deg <= ALC) {
        for (int i = t; i < deg; i += 256) sl[i] = (unsigned short)(es[r0 + i] >> 16);
        __syncthreads();

        float mx = -1e30f;
        int i = j;
        for (; i + 96 < deg; i += 128) {
            int s0 = sl[i], s1 = sl[i + 32], s2 = sl[i + 64], s3 = sl[i + 96];
            float a0 = dot16_q(qa, qb, kr + (size_t)s0 * ldsrc + h * DHEAD) * ph;
            float a1 = dot16_q(qa, qb, kr + (size_t)s1 * ldsrc + h * DHEAD) * ph;
            float a2 = dot16_q(qa, qb, kr + (size_t)s2 * ldsrc + h * DHEAD) * ph;
            float a3 = dot16_q(qa, qb, kr + (size_t)s3 * ldsrc + h * DHEAD) * ph;
            wl[(i)      * NHEAD + h] = a0;
            wl[(i + 32) * NHEAD + h] = a1;
            wl[(i + 64) * NHEAD + h] = a2;
            wl[(i + 96) * NHEAD + h] = a3;
            mx = fmaxf(mx, fmaxf(fmaxf(a0, a1), fmaxf(a2, a3)));
        }
        for (; i < deg; i += 32) {
            int s0 = sl[i];
            float a = dot16_q(qa, qb, kr + (size_t)s0 * ldsrc + h * DHEAD) * ph;
            wl[i * NHEAD + h] = a;
            mx = fmaxf(mx, a);
        }
        mx = fmaxf(mx, __shfl_xor(mx, 8));
        mx = fmaxf(mx, __shfl_xor(mx, 16));
        mx = fmaxf(mx, __shfl_xor(mx, 32));
        if (lane < 8) wred[wv][h] = mx;
        __syncthreads();
        float m = fmaxf(fmaxf(wred[0][h], wred[1][h]), fmaxf(wred[2][h], wred[3][h]));
        __syncthreads();

        float sm = 0.f;
        for (i = j; i < deg; i += 32) {
            float e = exp2f(wl[i * NHEAD + h] - m);
            wl[i * NHEAD + h] = e;
            sm += e;
        }
        sm += __shfl_xor(sm, 8);
        sm += __shfl_xor(sm, 16);
        sm += __shfl_xor(sm, 32);
        if (lane < 8) wred[wv][h] = sm;
        __syncthreads();
        if (t < 8) {
            float s = wred[0][t] + wred[1][t] + wred[2][t] + wred[3][t];
            sinv[t] = (s > 0.f) ? 1.0f / s : 0.f;
        }
        __syncthreads();

        int g = t >> 6, l = t & 63;
        int hh = l >> 3;
        float acc0 = 0.f, acc1 = 0.f;
        i = g;
        for (; i + 28 < deg; i += 32) {
            int e0 = sl[i],      e1 = sl[i + 4],  e2 = sl[i + 8],  e3 = sl[i + 12];
            int e4 = sl[i + 16], e5 = sl[i + 20], e6 = sl[i + 24], e7 = sl[i + 28];
            unsigned int u0 = *(const unsigned int*)(vr + (size_t)e0 * ldsrc + 2 * l);
            unsigned int u1 = *(const unsigned int*)(vr + (size_t)e1 * ldsrc + 2 * l);
            unsigned int u2 = *(const unsigned int*)(vr + (size_t)e2 * ldsrc + 2 * l);
            unsigned int u3 = *(const unsigned int*)(vr + (size_t)e3 * ldsrc + 2 * l);
            unsigned int u4 = *(const unsigned int*)(vr + (size_t)e4 * ldsrc + 2 * l);
            unsigned int u5 = *(const unsigned int*)(vr + (size_t)e5 * ldsrc + 2 * l);
            unsigned int u6 = *(const unsigned int*)(vr + (size_t)e6 * ldsrc + 2 * l);
            unsigned int u7 = *(const unsigned int*)(vr + (size_t)e7 * ldsrc + 2 * l);
            float w0 = wl[(i)      * NHEAD + hh], w1 = wl[(i + 4)  * NHEAD + hh];
            float w2 = wl[(i + 8)  * NHEAD + hh], w3 = wl[(i + 12) * NHEAD + hh];
            float w4 = wl[(i + 16) * NHEAD + hh], w5 = wl[(i + 20) * NHEAD + hh];
            float w6 = wl[(i + 24) * NHEAD + hh], w7 = wl[(i + 28) * NHEAD + hh];
            float2 v0 = b2x2(u0), v1 = b2x2(u1), v2 = b2x2(u2), v3 = b2x2(u3);
            float2 v4 = b2x2(u4), v5 = b2x2(u5), v6 = b2x2(u6), v7 = b2x2(u7);
            acc0 += w0 * v0.x + w1 * v1.x + w2 * v2.x + w3 * v3.x
                  + w4 * v4.x + w5 * v5.x + w6 * v6.x + w7 * v7.x;
            acc1 += w0 * v0.y + w1 * v1.y + w2 * v2.y + w3 * v3.y
                  + w4 * v4.y + w5 * v5.y + w6 * v6.y + w7 * v7.y;
        }
        for (; i < deg; i += 4) {
            int e0 = sl[i];
            unsigned int u0 = *(const unsigned int*)(vr + (size_t)e0 * ldsrc + 2 * l);
            float w0 = wl[i * NHEAD + hh];
            float2 v0 = b2x2(u0);
            acc0 += w0 * v0.x;
            acc1 += w0 * v0.y;
        }
        p3f[g][l][0] = acc0;
        p3f[g][l][1] = acc1;
        __syncthreads();
        if (t < 128) {
            int c = t;
            float v = p3f[0][c >> 1][c & 1] + p3f[1][c >> 1][c & 1]
                    + p3f[2][c >> 1][c & 1] + p3f[3][c >> 1][c & 1];
            agg[(size_t)n * CDIM + c] = f2b(gelu_fast(v * sinv[c >> 4]));
        }
    } else {
        float* p3 = (float*)p3f;
        float mx = -1e30f;
        for (int i = j; i < deg; i += 32) {
            int sn = es[r0 + i] >> 16;
            float a = dot16_q(qa, qb, kr + (size_t)sn * ldsrc + h * DHEAD) * ph;
            alpha[(size_t)(r0 + i) * NHEAD + h] = a;
            mx = fmaxf(mx, a);
        }
        mx = fmaxf(mx, __shfl_xor(mx, 8));
        mx = fmaxf(mx, __shfl_xor(mx, 16));
        mx = fmaxf(mx, __shfl_xor(mx, 32));
        if (lane < 8) wred[wv][h] = mx;
        __syncthreads();
        float m = fmaxf(fmaxf(wred[0][h], wred[1][h]), fmaxf(wred[2][h], wred[3][h]));
        __syncthreads();

        float sm = 0.f;
        for (int i = j; i < deg; i += 32) {
            size_t ai = (size_t)(r0 + i) * NHEAD + h;
            float e = exp2f(alpha[ai] - m);
            alpha[ai] = e;
            sm += e;
        }
        sm += __shfl_xor(sm, 8);
        sm += __shfl_xor(sm, 16);
        sm += __shfl_xor(sm, 32);
        if (lane < 8) wred[wv][h] = sm;
        __syncthreads();
        if (t < 8) {
            float s = wred[0][t] + wred[1][t] + wred[2][t] + wred[3][t];
            sinv[t] = (s > 0.f) ? 1.0f / s : 0.f;
        }
        __syncthreads();

        int c = t & 127, half = t >> 7;
        float hsi = sinv[c >> 4];
        float acc = 0.f;
        int i = half;
        for (; i + 6 < deg; i += 8) {
            unsigned int e0 = es[r0 + i],     e1 = es[r0 + i + 2];
            unsigned int e2 = es[r0 + i + 4], e3 = es[r0 + i + 6];
            float w0 = alpha[(size_t)(r0 + i)     * NHEAD + (c >> 4)];
            float w1 = alpha[(size_t)(r0 + i + 2) * NHEAD + (c >> 4)];
            float w2 = alpha[(size_t)(r0 + i + 4) * NHEAD + (c >> 4)];
            float w3 = alpha[(size_t)(r0 + i + 6) * NHEAD + (c >> 4)];
            float v0 = b2f(vr[(size_t)(e0 >> 16) * ldsrc + c]);
            float v1 = b2f(vr[(size_t)(e1 >> 16) * ldsrc + c]);
            float v2 = b2f(vr[(size_t)(e2 >> 16) * ldsrc + c]);
            float v3 = b2f(vr[(size_t)(e3 >> 16) * ldsrc + c]);
            acc += w0 * v0 + w1 * v1 + w2 * v2 + w3 * v3;
        }
        for (; i < deg; i += 2) {
            unsigned int e0 = es[r0 + i];
            float w0 = alpha[(size_t)(r0 + i) * NHEAD + (c >> 4)];
            acc += w0 * b2f(vr[(size_t)(e0 >> 16) * ldsrc + c]);
        }
        p3[t] = acc * hsi;
        __syncthreads();
        if (half == 0) agg[(size_t)n * CDIM + c] = f2b(gelu_fast(p3[c] + p3[128 + c]));
    }
}

// ---------------------------------------------------------------------------
// agg2 kernel (patient-dst), one wave per patient.
// ---------------------------------------------------------------------------
__global__ __launch_bounds__(256) void agg2_kernel(
    const int* __restrict__ rp1, const unsigned int* __restrict__ es1,
    const int* __restrict__ rp3, const unsigned int* __restrict__ es3,
    const unsigned short* __restrict__ q, int ldq,
    const unsigned short* __restrict__ kr1, const unsigned short* __restrict__ vr1, int ld1,
    const unsigned short* __restrict__ kr3, const unsigned short* __restrict__ vr3, int ld3,
    const float* __restrict__ prel1, const float* __restrict__ prel3,
    unsigned short* __restrict__ agg, int nd)
{
    __shared__ float wls[4][128 * NHEAD];
    __shared__ int slo[4][128];
    int wv  = threadIdx.x >> 6;
    int wid = (blockIdx.x * 256 + threadIdx.x) >> 6;
    int lane = threadIdx.x & 63;
    if (wid >= nd) return;
    float* wl = wls[wv];
    int* sl = slo[wv];
    int h = lane & 7, j = lane >> 3;
    int hc = lane >> 3;
    const unsigned short* qbase = q + (size_t)wid * ldq;

    int r0a = rp1[wid], degA = rp1[wid + 1] - r0a;
    int r0b = rp3[wid], degB = rp3[wid + 1] - r0b;

    float o0, o1;
    if (degA <= 64 && degB <= 64) {
        const unsigned short* qrow = qbase + h * DHEAD;
        uint4 qa = ((const uint4*)qrow)[0], qb = ((const uint4*)qrow)[1];
        float phA = prel1[h] * 0.25f * LOG2E;
        float phB = prel3[h] * 0.25f * LOG2E;
        int dOfs = (int)(kr3 - kr1);
        float mA = -1e30f, mB = -1e30f;
        for (int i = j; i < degA; i += 8) {
            int sn = es1[r0a + i] >> 16;
            int off = sn * ld1;
            float a = dot16_q(qa, qb, kr1 + off + h * DHEAD) * phA;
            wl[i * NHEAD + h] = a;
            if (h == 0) sl[i] = off;
            mA = fmaxf(mA, a);
        }
        for (int i = j; i < degB; i += 8) {
            int sn = es3[r0b + i] >> 16;
            int off = sn * ld3;
            float a = dot16_q(qa, qb, kr3 + off + h * DHEAD) * phB;
            wl[(degA + i) * NHEAD + h] = a;
            if (h == 0) sl[degA + i] = dOfs + off;
            mB = fmaxf(mB, a);
        }
        mA = fmaxf(mA, __shfl_xor(mA, 8));   mB = fmaxf(mB, __shfl_xor(mB, 8));
        mA = fmaxf(mA, __shfl_xor(mA, 16));  mB = fmaxf(mB, __shfl_xor(mB, 16));
        mA = fmaxf(mA, __shfl_xor(mA, 32));  mB = fmaxf(mB, __shfl_xor(mB, 32));

        int dtot = degA + degB;
        float sA = 0.f, sB = 0.f;
        for (int i = j; i < dtot; i += 8) {
            bool isA = i < degA;
            float e = exp2f(wl[i * NHEAD + h] - (isA ? mA : mB));
            wl[i * NHEAD + h] = e;
            sA += isA ? e : 0.f;
            sB += isA ? 0.f : e;
        }
        sA += __shfl_xor(sA, 8);   sB += __shfl_xor(sB, 8);
        sA += __shfl_xor(sA, 16);  sB += __shfl_xor(sB, 16);
        sA += __shfl_xor(sA, 32);  sB += __shfl_xor(sB, 32);
        float siA = (sA > 0.f) ? 1.0f / sA : 0.f;
        float siB = (sB > 0.f) ? 1.0f / sB : 0.f;
        float siAh = __shfl(siA, hc);
        float siBh = __shfl(siB, hc);

        float accA0 = 0.f, accA1 = 0.f, accB0 = 0.f, accB1 = 0.f;
        int i = 0;
        for (; i + 4 <= degA; i += 4) {
            int oo0 = sl[i + 0], oo1 = sl[i + 1], oo2 = sl[i + 2], oo3 = sl[i + 3];
            unsigned int u0 = *(const unsigned int*)(vr1 + oo0 + 2 * lane);
            unsigned int u1 = *(const unsigned int*)(vr1 + oo1 + 2 * lane);
            unsigned int u2 = *(const unsigned int*)(vr1 + oo2 + 2 * lane);
            unsigned int u3 = *(const unsigned int*)(vr1 + oo3 + 2 * lane);
            float w0 = wl[(i + 0) * NHEAD + hc];
            float w1 = wl[(i + 1) * NHEAD + hc];
            float w2 = wl[(i + 2) * NHEAD + hc];
            float w3 = wl[(i + 3) * NHEAD + hc];
            float2 v0 = b2x2(u0), v1 = b2x2(u1), v2 = b2x2(u2), v3 = b2x2(u3);
            accA0 += w0 * v0.x + w1 * v1.x + w2 * v2.x + w3 * v3.x;
            accA1 += w0 * v0.y + w1 * v1.y + w2 * v2.y + w3 * v3.y;
        }
        for (; i < degA; i++) {
            int oo = sl[i];
            unsigned int u0 = *(const unsigned int*)(vr1 + oo + 2 * lane);
            float w0 = wl[i * NHEAD + hc];
            float2 v0 = b2x2(u0);
            accA0 += w0 * v0.x; accA1 += w0 * v0.y;
        }
        for (; i + 4 <= dtot; i += 4) {
            int oo0 = sl[i + 0], oo1 = sl[i + 1], oo2 = sl[i + 2], oo3 = sl[i + 3];
            unsigned int u0 = *(const unsigned int*)(vr1 + oo0 + 2 * lane);
            unsigned int u1 = *(const unsigned int*)(vr1 + oo1 + 2 * lane);
            unsigned int u2 = *(const unsigned int*)(vr1 + oo2 + 2 * lane);
            unsigned int u3 = *(const unsigned int*)(vr1 + oo3 + 2 * lane);
            float w0 = wl[(i + 0) * NHEAD + hc];
            float w1 = wl[(i + 1) * NHEAD + hc];
            float w2 = wl[(i + 2) * NHEAD + hc];
            float w3 = wl[(i + 3) * NHEAD + hc];
            float2 v0 = b2x2(u0), v1 = b2x2(u1), v2 = b2x2(u2), v3 = b2x2(u3);
            accB0 += w0 * v0.x + w1 * v1.x + w2 * v2.x + w3 * v3.x;
            accB1 += w0 * v0.y + w1 * v1.y + w2 * v2.y + w3 * v3.y;
        }
        for (; i < dtot; i++) {
            int oo = sl[i];
            unsigned int u0 = *(const unsigned int*)(vr1 + oo + 2 * lane);
            float w0 = wl[i * NHEAD + hc];
            float2 v0 = b2x2(u0);
            accB0 += w0 * v0.x; accB1 += w0 * v0.y;
        }
        o0 = accA0 * siAh + accB0 * siBh;
        o1 = accA1 * siAh + accB1 * siBh;
    } else {
        float acc0 = 0.f, acc1 = 0.f;
        #pragma unroll
        for (int rr = 0; rr < 2; rr++) {
            const unsigned int* es = rr ? es3 : es1;
            const unsigned short* kr = rr ? kr3 : kr1;
            const unsigned short* vr = rr ? vr3 : vr1;
            int ld = rr ? ld3 : ld1;
            const float* prel = rr ? prel3 : prel1;
            int r0 = rr ? r0b : r0a;
            int deg = rr ? degB : degA;
            if (deg <= 0) continue;
            const unsigned short* qrow = qbase + h * DHEAD;
            float ph = prel[h] * 0.25f * LOG2E;
            bool small = (deg <= 64);

            float m = -1e30f;
            for (int i = j; i < deg; i += 8) {
                int sn = es[r0 + i] >> 16;
                float a = dot16_bf(qrow, kr + (size_t)sn * ld + h * DHEAD) * ph;
                if (small) wl[i * NHEAD + h] = a;
                m = fmaxf(m, a);
            }
            m = fmaxf(m, __shfl_xor(m, 8));
            m = fmaxf(m, __shfl_xor(m, 16));
            m = fmaxf(m, __shfl_xor(m, 32));
            float s = 0.f;
            for (int i = j; i < deg; i += 8) {
                float a;
                if (small) a = wl[i * NHEAD + h];
                else {
                    int sn = es[r0 + i] >> 16;
                    a = dot16_bf(qrow, kr + (size_t)sn * ld + h * DHEAD) * ph;
                }
                float e = exp2f(a - m);
                if (small) wl[i * NHEAD + h] = e;
                s += e;
            }
            s += __shfl_xor(s, 8);
            s += __shfl_xor(s, 16);
            s += __shfl_xor(s, 32);
            float si = (s > 0.f) ? 1.0f / s : 0.f;
            if (small)
                for (int i = j; i < deg; i += 8)
                    wl[i * NHEAD + h] *= si;

            float m_hc  = __shfl(m, hc);
            float si_hc = __shfl(si, hc);
            float ph_hc = __shfl(ph, hc);
            const unsigned short* qrow_hc = qbase + hc * DHEAD;
            for (int i = 0; i < deg; i++) {
                unsigned int sv = es[r0 + i] >> 16;
                unsigned int pv = *(const unsigned int*)(vr + (size_t)sv * ld + 2 * lane);
                float2 v = b2x2(pv);
                float wgt;
                if (small) wgt = wl[i * NHEAD + hc];
                else {
                    float a = dot16_bf(qrow_hc, kr + (size_t)sv * ld + hc * DHEAD) * ph_hc;
                    wgt = exp2f(a - m_hc) * si_hc;
                }
                acc0 += wgt * v.x;
                acc1 += wgt * v.y;
            }
        }
        o0 = acc0; o1 = acc1;
    }
    unsigned int packed = (unsigned int)f2b(gelu_fast(o0))
                        | ((unsigned int)f2b(gelu_fast(o1)) << 16);
    *(unsigned int*)(agg + (size_t)wid * CDIM + 2 * lane) = packed;
}

// ---------------------------------------------------------------------------
extern "C" void kernel_launch(void* const* d_in, const int* in_sizes, int n_in,
                              void* d_out, int out_size, void* d_ws, size_t ws_size,
                              hipStream_t stream)
{
    const float* x_patient = (const float*)d_in[0];
    const float* w_in      = (const float*)d_in[1];
    const float* b_in      = (const float*)d_in[2];
    const float* emb_icd   = (const float*)d_in[3];
    const float* emb_ndc   = (const float*)d_in[4];
    const float* kw        = (const float*)d_in[5];
    const float* kbias     = (const float*)d_in[6];
    const float* qw        = (const float*)d_in[7];
    const float* qbias     = (const float*)d_in[8];
    const float* vw        = (const float*)d_in[9];
    const float* vbias     = (const float*)d_in[10];
    const float* aw        = (const float*)d_in[11];
    const float* abias     = (const float*)d_in[12];
    const float* skip      = (const float*)d_in[13];
    const float* a_rel     = (const float*)d_in[14];
    const float* m_rel     = (const float*)d_in[15];
    const float* p_rel     = (const float*)d_in[16];
    const float* w_out     = (const float*)d_in[17];
    const float* b_out     = (const float*)d_in[18];
    const int*   x_icd     = (const int*)d_in[19];
    const int*   x_ndc     = (const int*)d_in[20];
    const int* esrc[4] = {(const int*)d_in[21], (const int*)d_in[23],
                          (const int*)d_in[25], (const int*)d_in[27]};
    const int* edst[4] = {(const int*)d_in[22], (const int*)d_in[24],
                          (const int*)d_in[26], (const int*)d_in[28]};

    const int sizes[3] = {NPAT, NICD, NNDC};

    char* p = (char*)d_ws;
    auto alloc = [&](size_t bytes) -> void* {
        void* r = (void*)p;
        p += (bytes + 255) & ~(size_t)255;
        return r;
    };

    unsigned short *xb[3];
    for (int t = 0; t < 3; t++) xb[t] = (unsigned short*)alloc((size_t)sizes[t] * CDIM * 2);
    unsigned short* P0 = (unsigned short*)alloc((size_t)NPAT * 640 * 2);
    unsigned short* P1 = (unsigned short*)alloc((size_t)NICD * 384 * 2);
    unsigned short* P2 = (unsigned short*)alloc((size_t)NNDC * 384 * 2);
    unsigned short* aggbase = (unsigned short*)alloc((size_t)(NPAT + NICD + NNDC) * CDIM * 2);
    unsigned short* agg[3];
    agg[0] = aggbase;
    agg[1] = aggbase + (size_t)NPAT * CDIM;
    agg[2] = agg[1] + (size_t)NICD * CDIM;
    float*  alphabuf  = (float*)alloc((size_t)NEDGE * NHEAD * 4);
    float*  alphabuf2 = (float*)alloc((size_t)NEDGE * NHEAD * 4);
    unsigned int* esbig = (unsigned int*)alloc((size_t)4 * NEDGE * 4);
    int* rowptr[4];
    rowptr[0] = (int*)alloc((size_t)(NICD + 1) * 4);
    rowptr[1] = (int*)alloc((size_t)(NPAT + 1) * 4);
    rowptr[2] = (int*)alloc((size_t)(NNDC + 1) * 4);
    rowptr[3] = (int*)alloc((size_t)(NPAT + 1) * 4);
    int* deg    = (int*)alloc((size_t)NTOT * 4);
    int* cursor = (int*)alloc((size_t)NTOT * 4);
    int* part   = (int*)alloc((size_t)256 * 4);
    unsigned short* Wb0   = (unsigned short*)alloc((size_t)2 * 640 * 128 * 2);
    unsigned short* Wb1   = (unsigned short*)alloc((size_t)2 * 384 * 128 * 2);
    unsigned short* Wb2   = (unsigned short*)alloc((size_t)2 * 384 * 128 * 2);
    unsigned short* Wtaw  = (unsigned short*)alloc((size_t)6 * 128 * 128 * 2);
    unsigned short* Wtin  = (unsigned short*)alloc((size_t)128 * 128 * 2);
    unsigned short* Wtout = (unsigned short*)alloc((size_t)OUTN * 128 * 2);
    float* bb0 = (float*)alloc((size_t)2 * 640 * 4);
    float* bb1 = (float*)alloc((size_t)2 * 384 * 4);
    float* bb2 = (float*)alloc((size_t)2 * 384 * 4);
    unsigned int* esRel[4];
    for (int r = 0; r < 4; r++) esRel[r] = esbig + (size_t)r * NEDGE;

    // GEMM3 geometry
    const int ntP0 = 640 / 64, nwgP0 = ((NPAT + 63) / 64) * ntP0;
    const int ntP1 = 384 / 64, nwgP1 = ((NICD + 63) / 64) * ntP1;
    const int ntP2 = 384 / 64, nwgP2 = ((NNDC + 63) / 64) * ntP2;
    const int ntS  = 128 / 64;
    const int nwgS0 = ((NPAT + 63) / 64) * ntS;
    const int nwgS1 = ((NICD + 63) / 64) * ntS;
    const int nwgS2 = ((NNDC + 63) / 64) * ntS;

    // ---- 1: merged prep ----
    prep_all_kernel<<<dim3(PB_G), dim3(256), 0, stream>>>(
        qw, aw, w_in, w_out, Wb0, Wb1, Wb2, Wtaw, Wtin, Wtout,
        kw, vw, a_rel, m_rel, kbias, vbias, bb0, bb1, bb2, qbias,
        deg, emb_icd, x_icd, xb[1], emb_ndc, x_ndc, xb[2]);

    // ---- 2: hist4 + input projection (independent, merged) ----
    hist_in_kernel<<<dim3(256 + INP_NWG), dim3(256), 0, stream>>>(
        edst[0], edst[1], edst[2], edst[3], deg,
        x_patient, Wtin, b_in, xb[0]);

    // ---- 3-4: scans ----
    scanA_kernel<<<NB_SCAN, 256, 0, stream>>>(deg, part, NTOT);
    scanC2_kernel<<<NB_SCAN, 256, 0, stream>>>(deg, part,
        rowptr[0], rowptr[1], rowptr[2], rowptr[3], cursor, NTOT);

    // ---- 5: scatter + layer-0 projection GEMMs (independent, merged) ----
    scat_proj_kernel<<<dim3(SCAT_N + nwgP0 + nwgP1 + nwgP2), dim3(256), 0, stream>>>(
        esrc[0], edst[0], esrc[1], edst[1], esrc[2], edst[2], esrc[3], edst[3],
        cursor, esbig,
        xb[0], Wb0, bb0, P0, NPAT, 640, ntP0, nwgP0,
        xb[1], Wb1, bb1, P1, NICD, 384, ntP1, nwgP0 + nwgP1,
        xb[2], Wb2, bb2, P2, NNDC, 384, ntP2);

    // ---- layers ----
    for (int l = 0; l < NLAYER; l++) {
        if (l > 0) {
            gemm3_kernel<<<dim3(nwgP0 + nwgP1 + nwgP2), dim3(256), 0, stream>>>(
                xb[0], Wb0 + (size_t)l * 640 * 128, bb0 + (size_t)l * 640, P0,
                NPAT, 640, ntP0, nwgP0,
                xb[1], Wb1 + (size_t)l * 384 * 128, bb1 + (size_t)l * 384, P1,
                NICD, 384, ntP1, nwgP0 + nwgP1,
                xb[2], Wb2 + (size_t)l * 384 * 128, bb2 + (size_t)l * 384, P2,
                NNDC, 384, ntP2,
                nullptr, 0, 0, 0);
        }

        seg_kernel<<<dim3(NNDC, 2), dim3(256), 0, stream>>>(
            rowptr[0], esRel[0], P1, 384, P0 + 128, P0 + 256, 640,
            p_rel + (size_t)(l * 4 + 0) * NHEAD, alphabuf, agg[1], NICD,
            rowptr[2], esRel[2], P2, 384, P0 + 384, P0 + 512, 640,
            p_rel + (size_t)(l * 4 + 2) * NHEAD, alphabuf2, agg[2], NNDC);

        agg2_kernel<<<dim3(NAGG), dim3(256), 0, stream>>>(
            rowptr[1], esRel[1], rowptr[3], esRel[3],
            P0, 640, P1 + 128, P1 + 256, 384, P2 + 128, P2 + 256, 384,
            p_rel + (size_t)(l * 4 + 1) * NHEAD, p_rel + (size_t)(l * 4 + 3) * NHEAD,
            agg[0], NPAT);

        gemm3_kernel<<<dim3(nwgS0 + nwgS1 + nwgS2), dim3(256), 0, stream>>>(
            agg[0], Wtaw + (size_t)(l * 3 + 0) * 16384, abias + (size_t)(l * 3 + 0) * 128, xb[0],
            NPAT, 128, ntS, nwgS0,
            agg[1], Wtaw + (size_t)(l * 3 + 1) * 16384, abias + (size_t)(l * 3 + 1) * 128, xb[1],
            NICD, 128, ntS, nwgS0 + nwgS1,
            agg[2], Wtaw + (size_t)(l * 3 + 2) * 16384, abias + (size_t)(l * 3 + 2) * 128, xb[2],
            NNDC, 128, ntS,
            skip, l * 3 + 0, l * 3 + 1, l * 3 + 2);
    }

    // ---- output head (fp32 out) ----
    {
        int ntile = (OUTN + 63) / 64;
        int nwg = ((NPAT + 63) / 64) * ntile;
        gemm_xs<<<dim3(nwg), dim3(256), 0, stream>>>(xb[0], 0, 128, Wtout, b_out,
            d_out, 1, OUTN, NPAT, OUTN, 2, ntile, nullptr, 0, nullptr, 0);
    }
}